// Round 5
// baseline (444.590 us; speedup 1.0000x reference)
//
#include <hip/hip_runtime.h>
#include <hip/hip_bf16.h>
#include <stdint.h>

#define T_TOK 4096
#define DD 1024
#define EE 8
#define CC 512
#define FF 2752
#define FP 2816

typedef __attribute__((ext_vector_type(8))) short bf16x8;
typedef __attribute__((ext_vector_type(4))) float f32x4;
typedef __attribute__((ext_vector_type(4))) unsigned short us4;

__device__ __forceinline__ float bf2f(unsigned short u) {
  union { float f; unsigned int i; } v; v.i = ((unsigned int)u) << 16; return v.f;
}
__device__ __forceinline__ unsigned short f2bf(float f) {
  union { float f; unsigned int i; } v; v.f = f;
  unsigned int r = v.i + 0x7fffu + ((v.i >> 16) & 1u);
  return (unsigned short)(r >> 16);
}

#define GLDS16(g, l) __builtin_amdgcn_global_load_lds( \
    (const __attribute__((address_space(1))) void*)(g), \
    (__attribute__((address_space(3))) void*)(l), 16, 0, 0)

// Staging swizzle (round 3, verified): stage-lane l fetches row (l>>2),
// 16B-chunk ((l&3)^((l>>3)&3)); read lane (fr,fq) at fr*64B + (fq^((fr>>1)&3))*16B.
#define STG_CHUNK(l) (((l & 3) ^ ((l >> 3) & 3)) * 8)
#define RD_OFF(fr, fq) ((fr) * 32 + (((fq) ^ (((fr) >> 1) & 3)) * 8))

// ---------------- weight transpose + f32->bf16 -------------------
// z in [0,9): z<8 -> expert slab z of in/out; z==8 -> residual in2/out2.
__global__ __launch_bounds__(256)
void transpose_k(const float* __restrict__ in, const float* __restrict__ in2,
                 unsigned short* __restrict__ out, unsigned short* __restrict__ out2,
                 int R, int C, long inStride, long outStride) {
  __shared__ unsigned short sm[64][66];
  int b = blockIdx.z;
  if (b < EE) { in += (long)b * inStride; out += (long)b * outStride; }
  else { in = in2; out = out2; }
  int cb = blockIdx.x * 64, rb = blockIdx.y * 64;
  int t = threadIdx.x;
  int rr = t >> 4, c4 = (t & 15) * 4;
#pragma unroll
  for (int i = 0; i < 4; ++i) {
    int r = rr + i * 16;
    float4 v = *(const float4*)(in + (long)(rb + r) * C + cb + c4);
    us4 o; o.x = f2bf(v.x); o.y = f2bf(v.y); o.z = f2bf(v.z); o.w = f2bf(v.w);
    *(us4*)&sm[r][c4] = o;
  }
  __syncthreads();
  int r4 = (t & 15) * 4, cc = t >> 4;
#pragma unroll
  for (int i = 0; i < 4; ++i) {
    int c = cc + i * 16;
    us4 o;
    o.x = sm[r4 + 0][c]; o.y = sm[r4 + 1][c];
    o.z = sm[r4 + 2][c]; o.w = sm[r4 + 3][c];
    *(us4*)(out + (long)(cb + c) * R + rb + r4) = o;
  }
}

__global__ void zero_me_k(float* me) { if (threadIdx.x < EE) me[threadIdx.x] = 0.0f; }

// ---------------- gating ----------------
__global__ void gate_k(const float* __restrict__ x, const float* __restrict__ wg,
                       const float* __restrict__ cw, const float* __restrict__ cbv,
                       int* __restrict__ idx, float* __restrict__ gatev,
                       float* __restrict__ coef, float* __restrict__ me_sum) {
  int tid = threadIdx.x, lane = tid & 63, wv = tid >> 6;
  int t = blockIdx.x * 4 + wv;
  const float* xr = x + (long)t * DD;
  float acc[EE] = {0,0,0,0,0,0,0,0};
  float c0 = 0.0f, c1 = 0.0f;
  for (int d = lane; d < DD; d += 64) {
    float xv = xr[d];
#pragma unroll
    for (int e = 0; e < EE; ++e) acc[e] += xv * wg[d * EE + e];
    c0 += xv * cw[d * 2 + 0];
    c1 += xv * cw[d * 2 + 1];
  }
#pragma unroll
  for (int o = 32; o > 0; o >>= 1) {
#pragma unroll
    for (int e = 0; e < EE; ++e) acc[e] += __shfl_xor(acc[e], o);
    c0 += __shfl_xor(c0, o);
    c1 += __shfl_xor(c1, o);
  }
  __shared__ float sme[EE];
  if (tid < EE) sme[tid] = 0.0f;
  __syncthreads();
  if (lane == 0) {
    float m = acc[0]; int am = 0;
#pragma unroll
    for (int e = 1; e < EE; ++e) if (acc[e] > m) { m = acc[e]; am = e; }
    float g[EE]; float s = 0.0f;
#pragma unroll
    for (int e = 0; e < EE; ++e) { g[e] = __expf(acc[e] - m); s += g[e]; }
    float inv = 1.0f / s;
    idx[t] = am;
    gatev[t] = g[am] * inv;
#pragma unroll
    for (int e = 0; e < EE; ++e) atomicAdd(&sme[e], g[e] * inv);
    float l0 = c0 + cbv[0], l1 = c1 + cbv[1];
    float mm = fmaxf(l0, l1);
    float e0 = __expf(l0 - mm), e1 = __expf(l1 - mm);
    float is = 1.0f / (e0 + e1);
    coef[t * 2 + 0] = e0 * is;
    coef[t * 2 + 1] = e1 * is;
  }
  __syncthreads();
  if (tid < EE) atomicAdd(&me_sum[tid], sme[tid]);
}

// ---------------- capacity scan ----------------
__global__ void scan_k(const int* __restrict__ idx, const float* __restrict__ me_sum,
                       int* __restrict__ slot, int* __restrict__ tok,
                       float* __restrict__ out_tail) {
  __shared__ int sidx[T_TOK];
  __shared__ int counts[EE];
  int tid = threadIdx.x;
  for (int i = tid; i < T_TOK; i += 512) sidx[i] = idx[i];
  __syncthreads();
  int e = tid >> 6, lane = tid & 63;
  int base = 0;
  for (int it = 0; it < T_TOK / 64; ++it) {
    int t = it * 64 + lane;
    bool f = (sidx[t] == e);
    unsigned long long m = __ballot(f);
    if (f) {
      int loc = base + __popcll(m & ((1ull << lane) - 1ull));
      slot[t] = (loc < CC) ? loc : -1;
      if (loc < CC) tok[e * CC + loc] = t;
    }
    base += __popcll(m);
  }
  if (lane == 0) counts[e] = base;
  __syncthreads();
  int filled = min(counts[e], CC);
  for (int c = filled + lane; c < CC; c += 64) tok[e * CC + c] = -1;
  if (tid == 0) {
    float la = 0.0f;
    for (int i = 0; i < EE; ++i) la += me_sum[i] * (float)counts[i];
    la *= (float)EE / ((float)T_TOK * (float)T_TOK);
    out_tail[0] = la;
    for (int i = 0; i < EE; ++i) out_tail[1 + i] = (float)counts[i];
  }
}

// ---------------- gather + bf16 convert ----------------
__global__ void gather_k(const float* __restrict__ x, const int* __restrict__ tok,
                         unsigned short* __restrict__ xb, unsigned short* __restrict__ xe) {
  int r = blockIdx.x, tid = threadIdx.x;
  int d = tid * 4;
  if (r < T_TOK) {
    float4 v = *(const float4*)(x + (long)r * DD + d);
    us4 o; o.x = f2bf(v.x); o.y = f2bf(v.y); o.z = f2bf(v.z); o.w = f2bf(v.w);
    *(us4*)(xb + (long)r * DD + d) = o;
  } else {
    int s = r - T_TOK;
    int t = tok[s];
    us4 o = {0, 0, 0, 0};
    if (t >= 0) {
      float4 v = *(const float4*)(x + (long)t * DD + d);
      o.x = f2bf(v.x); o.y = f2bf(v.y); o.z = f2bf(v.z); o.w = f2bf(v.w);
    }
    *(us4*)(xe + (long)s * DD + d) = o;
  }
}

// ---------------- GEMM1: H = silu(A@W1)*(A@W3) -------------------
// BM=256, BN=64 (dual B1/B3), BK=64, 4 waves, single-buffer, frag-ordered LDS.
// Per K-iter per wave: 64 MFMA vs 1 barrier-pair (4x the round-3 amortization).
__global__ __launch_bounds__(256)
void gemm1_k(const unsigned short* __restrict__ xe, const unsigned short* __restrict__ xb,
             const unsigned short* __restrict__ w1t, const unsigned short* __restrict__ w3t,
             const unsigned short* __restrict__ rw1t, const unsigned short* __restrict__ rw3t,
             unsigned short* __restrict__ He, unsigned short* __restrict__ Hr) {
  int lin = blockIdx.x;
  int work = (lin & 7) * 172 + (lin >> 3);   // 1376 blocks, 172 per XCD
  const unsigned short *A, *B1, *B3;
  unsigned short* H;
  int nt;
  if (work < 688) {                // experts: (e*43 + nt)*2 + mt
    int mt = work & 1;
    int q = work >> 1;
    nt = q % 43;
    int e = q / 43;
    A = xe + (size_t)(e * 2 + mt) * 256 * DD;
    B1 = w1t + (size_t)e * FP * DD;
    B3 = w3t + (size_t)e * FP * DD;
    H = He + (size_t)(e * 2 + mt) * 256 * FF;
  } else {                         // residual: nt*16 + mt
    int q = work - 688;
    int mt = q & 15;
    nt = q >> 4;
    A = xb + (size_t)mt * 256 * DD;
    B1 = rw1t; B3 = rw3t;
    H = Hr + (size_t)mt * 256 * FF;
  }
  int n0 = nt * 64;

  __shared__ __align__(16) unsigned short As[256 * 64];   // 32 frags x 1KB
  __shared__ __align__(16) unsigned short B1s[64 * 64];   // 8 frags
  __shared__ __align__(16) unsigned short B3s[64 * 64];

  int tid = threadIdx.x, l = tid & 63, w = tid >> 6;
  int fr = l & 15, fq = l >> 4;
  int srow = l >> 2, soff = STG_CHUNK(l);

  f32x4 acc1[4][4] = {};
  f32x4 acc3[4][4] = {};

  for (int kt = 0; kt < DD / 64; ++kt) {
    int k0 = kt * 64;
    __syncthreads();
#pragma unroll
    for (int c = 0; c < 8; ++c) {            // A: frag f = ks*16+mi
      int f = c * 4 + w;
      int ks = f >> 4, mi = f & 15;
      GLDS16(A + (size_t)(mi * 16 + srow) * DD + k0 + ks * 32 + soff,
             (char*)As + f * 1024);
    }
#pragma unroll
    for (int c = 0; c < 2; ++c) {            // B: frag g = ks*4+ni
      int g = c * 4 + w;
      int ks = g >> 2, ni = g & 3;
      GLDS16(B1 + (size_t)(n0 + ni * 16 + srow) * DD + k0 + ks * 32 + soff,
             (char*)B1s + g * 1024);
      GLDS16(B3 + (size_t)(n0 + ni * 16 + srow) * DD + k0 + ks * 32 + soff,
             (char*)B3s + g * 1024);
    }
    __syncthreads();

#pragma unroll
    for (int ks = 0; ks < 2; ++ks) {
      bf16x8 af[4], b1f[4], b3f[4];
#pragma unroll
      for (int mi = 0; mi < 4; ++mi)
        af[mi] = *(const bf16x8*)(As + (ks * 16 + w * 4 + mi) * 512 + RD_OFF(fr, fq));
#pragma unroll
      for (int ni = 0; ni < 4; ++ni) {
        b1f[ni] = *(const bf16x8*)(B1s + (ks * 4 + ni) * 512 + RD_OFF(fr, fq));
        b3f[ni] = *(const bf16x8*)(B3s + (ks * 4 + ni) * 512 + RD_OFF(fr, fq));
      }
#pragma unroll
      for (int mi = 0; mi < 4; ++mi)
#pragma unroll
        for (int ni = 0; ni < 4; ++ni) {
          acc1[mi][ni] = __builtin_amdgcn_mfma_f32_16x16x32_bf16(af[mi], b1f[ni], acc1[mi][ni], 0, 0, 0);
          acc3[mi][ni] = __builtin_amdgcn_mfma_f32_16x16x32_bf16(af[mi], b3f[ni], acc3[mi][ni], 0, 0, 0);
        }
    }
  }

#pragma unroll
  for (int mi = 0; mi < 4; ++mi)
#pragma unroll
    for (int ni = 0; ni < 4; ++ni)
#pragma unroll
      for (int r = 0; r < 4; ++r) {
        int gm = w * 64 + mi * 16 + fq * 4 + r;
        int gn = n0 + ni * 16 + fr;
        float v1 = acc1[mi][ni][r], v3 = acc3[mi][ni][r];
        float h = v1 / (1.0f + __expf(-v1)) * v3;
        H[(size_t)gm * FF + gn] = f2bf(h);
      }
}

// ---------------- GEMM2: Y = H @ W2 ------------------------------
// BM=256, BN=128, BK=64, 4 waves, single-buffer, frag-ordered LDS.
__global__ __launch_bounds__(256)
void gemm2_k(const unsigned short* __restrict__ He, const unsigned short* __restrict__ Hr,
             const unsigned short* __restrict__ w2t, const unsigned short* __restrict__ rw2t,
             unsigned short* __restrict__ Ye, unsigned short* __restrict__ Yr) {
  int lin = blockIdx.x;
  int work = (lin & 7) * 32 + (lin >> 3);   // 256 blocks, 32 per XCD
  const unsigned short *A, *B;
  unsigned short* Y;
  int nt;
  if (work < 128) {                // experts: (e*8 + nt)*2 + mt
    int mt = work & 1;
    int q = work >> 1;
    nt = q & 7;
    int e = q >> 3;
    A = He + (size_t)(e * 2 + mt) * 256 * FF;
    B = w2t + (size_t)e * DD * FF;
    Y = Ye + (size_t)(e * 2 + mt) * 256 * DD;
  } else {                         // residual: nt*16 + mt
    int q = work - 128;
    int mt = q & 15;
    nt = q >> 4;
    A = Hr + (size_t)mt * 256 * FF;
    B = rw2t;
    Y = Yr + (size_t)mt * 256 * DD;
  }
  int n0 = nt * 128;

  __shared__ __align__(16) unsigned short As[256 * 64];   // 32 frags
  __shared__ __align__(16) unsigned short Bs[128 * 64];   // 16 frags

  int tid = threadIdx.x, l = tid & 63, w = tid >> 6;
  int fr = l & 15, fq = l >> 4;
  int srow = l >> 2, soff = STG_CHUNK(l);

  f32x4 acc[4][8] = {};

  for (int kt = 0; kt < FF / 64; ++kt) {     // 43 iters
    int k0 = kt * 64;
    __syncthreads();
#pragma unroll
    for (int c = 0; c < 8; ++c) {            // A: frag f = ks*16+mi
      int f = c * 4 + w;
      int ks = f >> 4, mi = f & 15;
      GLDS16(A + (size_t)(mi * 16 + srow) * FF + k0 + ks * 32 + soff,
             (char*)As + f * 1024);
    }
#pragma unroll
    for (int c = 0; c < 4; ++c) {            // B: frag g = ks*8+ni
      int g = c * 4 + w;
      int ks = g >> 3, ni = g & 7;
      GLDS16(B + (size_t)(n0 + ni * 16 + srow) * FF + k0 + ks * 32 + soff,
             (char*)Bs + g * 1024);
    }
    __syncthreads();

#pragma unroll
    for (int ks = 0; ks < 2; ++ks) {
      bf16x8 af[4], bfr[8];
#pragma unroll
      for (int mi = 0; mi < 4; ++mi)
        af[mi] = *(const bf16x8*)(As + (ks * 16 + w * 4 + mi) * 512 + RD_OFF(fr, fq));
#pragma unroll
      for (int ni = 0; ni < 8; ++ni)
        bfr[ni] = *(const bf16x8*)(Bs + (ks * 8 + ni) * 512 + RD_OFF(fr, fq));
#pragma unroll
      for (int mi = 0; mi < 4; ++mi)
#pragma unroll
        for (int ni = 0; ni < 8; ++ni)
          acc[mi][ni] = __builtin_amdgcn_mfma_f32_16x16x32_bf16(af[mi], bfr[ni], acc[mi][ni], 0, 0, 0);
    }
  }

#pragma unroll
  for (int mi = 0; mi < 4; ++mi)
#pragma unroll
    for (int ni = 0; ni < 8; ++ni)
#pragma unroll
      for (int r = 0; r < 4; ++r) {
        int gm = w * 64 + mi * 16 + fq * 4 + r;
        int gn = n0 + ni * 16 + fr;
        Y[(size_t)gm * DD + gn] = f2bf(acc[mi][ni][r]);
      }
}

// ---------------- combine ----------------------------------------
__global__ void combine_k(const unsigned short* __restrict__ Ye, const unsigned short* __restrict__ Yr,
                          const int* __restrict__ idx, const int* __restrict__ slot,
                          const float* __restrict__ gatev, const float* __restrict__ coef,
                          float* __restrict__ out) {
  int t = blockIdx.x, tid = threadIdx.x;
  int d = tid * 4;
  float c0 = coef[t * 2], c1 = coef[t * 2 + 1];
  int s = slot[t];
  float g = gatev[t] * c0;
  us4 vr = *(const us4*)(Yr + (size_t)t * DD + d);
  float4 o;
  if (s >= 0) {
    us4 ve = *(const us4*)(Ye + ((size_t)idx[t] * CC + s) * DD + d);
    o.x = g * bf2f(ve.x) + c1 * bf2f(vr.x);
    o.y = g * bf2f(ve.y) + c1 * bf2f(vr.y);
    o.z = g * bf2f(ve.z) + c1 * bf2f(vr.z);
    o.w = g * bf2f(ve.w) + c1 * bf2f(vr.w);
  } else {
    o.x = c1 * bf2f(vr.x);
    o.y = c1 * bf2f(vr.y);
    o.z = c1 * bf2f(vr.z);
    o.w = c1 * bf2f(vr.w);
  }
  *(float4*)(out + (size_t)t * DD + d) = o;
}

// ---------------- launch -----------------------------------------
extern "C" void kernel_launch(void* const* d_in, const int* in_sizes, int n_in,
                              void* d_out, int out_size, void* d_ws, size_t ws_size,
                              hipStream_t stream) {
  const float* x   = (const float*)d_in[0];
  const float* wg  = (const float*)d_in[1];
  const float* w1  = (const float*)d_in[2];
  const float* w3  = (const float*)d_in[3];
  const float* w2  = (const float*)d_in[4];
  const float* rw1 = (const float*)d_in[5];
  const float* rw3 = (const float*)d_in[6];
  const float* rw2 = (const float*)d_in[7];
  const float* cw  = (const float*)d_in[8];
  const float* cbv = (const float*)d_in[9];
  float* out = (float*)d_out;

  char* ws = (char*)d_ws;
  size_t o = 0;
  auto alloc = [&](size_t bytes) -> char* {
    char* p = ws + o; o = (o + bytes + 255) & ~(size_t)255; return p;
  };
  unsigned short* w1t  = (unsigned short*)alloc((size_t)EE * FP * DD * 2);
  unsigned short* w3t  = (unsigned short*)alloc((size_t)EE * FP * DD * 2);
  unsigned short* w2t  = (unsigned short*)alloc((size_t)EE * DD * FF * 2);
  unsigned short* rw1t = (unsigned short*)alloc((size_t)FP * DD * 2);
  unsigned short* rw3t = (unsigned short*)alloc((size_t)FP * DD * 2);
  unsigned short* rw2t = (unsigned short*)alloc((size_t)DD * FF * 2);
  unsigned short* xb   = (unsigned short*)alloc((size_t)T_TOK * DD * 2);
  unsigned short* xe   = (unsigned short*)alloc((size_t)T_TOK * DD * 2);
  unsigned short* He   = (unsigned short*)alloc((size_t)T_TOK * FF * 2);
  unsigned short* Hr   = (unsigned short*)alloc((size_t)T_TOK * FF * 2);
  unsigned short* Ye   = (unsigned short*)alloc((size_t)T_TOK * DD * 2);
  unsigned short* Yr   = (unsigned short*)alloc((size_t)T_TOK * DD * 2);
  int*   idxp  = (int*)alloc(T_TOK * 4);
  float* gatev = (float*)alloc(T_TOK * 4);
  int*   slotp = (int*)alloc(T_TOK * 4);
  int*   tokp  = (int*)alloc(EE * CC * 4);
  float* coefp = (float*)alloc(T_TOK * 2 * 4);
  float* mep   = (float*)alloc(256);
  if (o > ws_size) return;

  // merged expert + residual transposes (z = 9: 8 experts + 1 residual)
  transpose_k<<<dim3(43, 16, EE + 1), 256, 0, stream>>>(w1, rw1, w1t, rw1t, DD, FF, (long)DD * FF, (long)FP * DD);
  transpose_k<<<dim3(43, 16, EE + 1), 256, 0, stream>>>(w3, rw3, w3t, rw3t, DD, FF, (long)DD * FF, (long)FP * DD);
  transpose_k<<<dim3(16, 43, EE + 1), 256, 0, stream>>>(w2, rw2, w2t, rw2t, FF, DD, (long)FF * DD, (long)DD * FF);

  zero_me_k<<<1, 64, 0, stream>>>(mep);
  gate_k<<<T_TOK / 4, 256, 0, stream>>>(x, wg, cw, cbv, idxp, gatev, coefp, mep);
  scan_k<<<1, 512, 0, stream>>>(idxp, mep, slotp, tokp, out + (size_t)T_TOK * DD);
  gather_k<<<2 * T_TOK, 256, 0, stream>>>(x, tokp, xb, xe);
  gemm1_k<<<1376, 256, 0, stream>>>(xe, xb, w1t, w3t, rw1t, rw3t, He, Hr);
  gemm2_k<<<256, 256, 0, stream>>>(He, Hr, w2t, rw2t, Ye, Yr);
  combine_k<<<T_TOK, 256, 0, stream>>>(Ye, Yr, idxp, slotp, gatev, coefp, out);
}

// Round 6
// 303.195 us; speedup vs baseline: 1.4663x; 1.4663x over previous
//
#include <hip/hip_runtime.h>
#include <hip/hip_bf16.h>
#include <stdint.h>

#define T_TOK 4096
#define DD 1024
#define EE 8
#define CC 512
#define FF 2752
#define FP 2816

typedef __attribute__((ext_vector_type(8))) short bf16x8;
typedef __attribute__((ext_vector_type(4))) float f32x4;
typedef __attribute__((ext_vector_type(4))) unsigned short us4;

__device__ __forceinline__ float bf2f(unsigned short u) {
  union { float f; unsigned int i; } v; v.i = ((unsigned int)u) << 16; return v.f;
}
__device__ __forceinline__ unsigned short f2bf(float f) {
  union { float f; unsigned int i; } v; v.f = f;
  unsigned int r = v.i + 0x7fffu + ((v.i >> 16) & 1u);
  return (unsigned short)(r >> 16);
}

#define GLDS16(g, l) __builtin_amdgcn_global_load_lds( \
    (const __attribute__((address_space(1))) void*)(g), \
    (__attribute__((address_space(3))) void*)(l), 16, 0, 0)

// Verified swizzle (rounds 3-5): stage-lane l fetches row (l>>2), 16B-chunk
// ((l&3)^((l>>3)&3)); reader lane (fr,fq) at element fr*32 + (fq^((fr>>1)&3))*8.
#define STG_CHUNK(l) (((l & 3) ^ ((l >> 3) & 3)) * 8)
#define RD_OFF(fr, fq) ((fr) * 32 + (((fq) ^ (((fr) >> 1) & 3)) * 8))

#define BAR() do { asm volatile("" ::: "memory"); __builtin_amdgcn_s_barrier(); \
                   asm volatile("" ::: "memory"); } while (0)

// ---------------- weight transpose + f32->bf16 -------------------
__global__ __launch_bounds__(256)
void transpose_k(const float* __restrict__ in, const float* __restrict__ in2,
                 unsigned short* __restrict__ out, unsigned short* __restrict__ out2,
                 int R, int C, long inStride, long outStride) {
  __shared__ unsigned short sm[64][66];
  int b = blockIdx.z;
  if (b < EE) { in += (long)b * inStride; out += (long)b * outStride; }
  else { in = in2; out = out2; }
  int cb = blockIdx.x * 64, rb = blockIdx.y * 64;
  int t = threadIdx.x;
  int rr = t >> 4, c4 = (t & 15) * 4;
#pragma unroll
  for (int i = 0; i < 4; ++i) {
    int r = rr + i * 16;
    float4 v = *(const float4*)(in + (long)(rb + r) * C + cb + c4);
    us4 o; o.x = f2bf(v.x); o.y = f2bf(v.y); o.z = f2bf(v.z); o.w = f2bf(v.w);
    *(us4*)&sm[r][c4] = o;
  }
  __syncthreads();
  int r4 = (t & 15) * 4, cc = t >> 4;
#pragma unroll
  for (int i = 0; i < 4; ++i) {
    int c = cc + i * 16;
    us4 o;
    o.x = sm[r4 + 0][c]; o.y = sm[r4 + 1][c];
    o.z = sm[r4 + 2][c]; o.w = sm[r4 + 3][c];
    *(us4*)(out + (long)(cb + c) * R + rb + r4) = o;
  }
}

__global__ void zero_me_k(float* me) { if (threadIdx.x < EE) me[threadIdx.x] = 0.0f; }

// ---------------- gating ----------------
__global__ void gate_k(const float* __restrict__ x, const float* __restrict__ wg,
                       const float* __restrict__ cw, const float* __restrict__ cbv,
                       int* __restrict__ idx, float* __restrict__ gatev,
                       float* __restrict__ coef, float* __restrict__ me_sum) {
  int tid = threadIdx.x, lane = tid & 63, wv = tid >> 6;
  int t = blockIdx.x * 4 + wv;
  const float* xr = x + (long)t * DD;
  float acc[EE] = {0,0,0,0,0,0,0,0};
  float c0 = 0.0f, c1 = 0.0f;
  for (int d = lane; d < DD; d += 64) {
    float xv = xr[d];
#pragma unroll
    for (int e = 0; e < EE; ++e) acc[e] += xv * wg[d * EE + e];
    c0 += xv * cw[d * 2 + 0];
    c1 += xv * cw[d * 2 + 1];
  }
#pragma unroll
  for (int o = 32; o > 0; o >>= 1) {
#pragma unroll
    for (int e = 0; e < EE; ++e) acc[e] += __shfl_xor(acc[e], o);
    c0 += __shfl_xor(c0, o);
    c1 += __shfl_xor(c1, o);
  }
  __shared__ float sme[EE];
  if (tid < EE) sme[tid] = 0.0f;
  __syncthreads();
  if (lane == 0) {
    float m = acc[0]; int am = 0;
#pragma unroll
    for (int e = 1; e < EE; ++e) if (acc[e] > m) { m = acc[e]; am = e; }
    float g[EE]; float s = 0.0f;
#pragma unroll
    for (int e = 0; e < EE; ++e) { g[e] = __expf(acc[e] - m); s += g[e]; }
    float inv = 1.0f / s;
    idx[t] = am;
    gatev[t] = g[am] * inv;
#pragma unroll
    for (int e = 0; e < EE; ++e) atomicAdd(&sme[e], g[e] * inv);
    float l0 = c0 + cbv[0], l1 = c1 + cbv[1];
    float mm = fmaxf(l0, l1);
    float e0 = __expf(l0 - mm), e1 = __expf(l1 - mm);
    float is = 1.0f / (e0 + e1);
    coef[t * 2 + 0] = e0 * is;
    coef[t * 2 + 1] = e1 * is;
  }
  __syncthreads();
  if (tid < EE) atomicAdd(&me_sum[tid], sme[tid]);
}

// ---------------- capacity scan ----------------
__global__ void scan_k(const int* __restrict__ idx, const float* __restrict__ me_sum,
                       int* __restrict__ slot, int* __restrict__ tok,
                       float* __restrict__ out_tail) {
  __shared__ int sidx[T_TOK];
  __shared__ int counts[EE];
  int tid = threadIdx.x;
  for (int i = tid; i < T_TOK; i += 512) sidx[i] = idx[i];
  __syncthreads();
  int e = tid >> 6, lane = tid & 63;
  int base = 0;
  for (int it = 0; it < T_TOK / 64; ++it) {
    int t = it * 64 + lane;
    bool f = (sidx[t] == e);
    unsigned long long m = __ballot(f);
    if (f) {
      int loc = base + __popcll(m & ((1ull << lane) - 1ull));
      slot[t] = (loc < CC) ? loc : -1;
      if (loc < CC) tok[e * CC + loc] = t;
    }
    base += __popcll(m);
  }
  if (lane == 0) counts[e] = base;
  __syncthreads();
  int filled = min(counts[e], CC);
  for (int c = filled + lane; c < CC; c += 64) tok[e * CC + c] = -1;
  if (tid == 0) {
    float la = 0.0f;
    for (int i = 0; i < EE; ++i) la += me_sum[i] * (float)counts[i];
    la *= (float)EE / ((float)T_TOK * (float)T_TOK);
    out_tail[0] = la;
    for (int i = 0; i < EE; ++i) out_tail[1 + i] = (float)counts[i];
  }
}

// ---------------- gather + bf16 convert ----------------
__global__ void gather_k(const float* __restrict__ x, const int* __restrict__ tok,
                         unsigned short* __restrict__ xb, unsigned short* __restrict__ xe) {
  int r = blockIdx.x, tid = threadIdx.x;
  int d = tid * 4;
  if (r < T_TOK) {
    float4 v = *(const float4*)(x + (long)r * DD + d);
    us4 o; o.x = f2bf(v.x); o.y = f2bf(v.y); o.z = f2bf(v.z); o.w = f2bf(v.w);
    *(us4*)(xb + (long)r * DD + d) = o;
  } else {
    int s = r - T_TOK;
    int t = tok[s];
    us4 o = {0, 0, 0, 0};
    if (t >= 0) {
      float4 v = *(const float4*)(x + (long)t * DD + d);
      o.x = f2bf(v.x); o.y = f2bf(v.y); o.z = f2bf(v.z); o.w = f2bf(v.w);
    }
    *(us4*)(xe + (long)s * DD + d) = o;
  }
}

// ---------------- GEMM1: H = silu(A@W1)*(A@W3) -------------------
// BM=256, BN=128, BK=64, 8 waves, dbuf LDS, counted-vmcnt 4-phase pipeline.
// LDS: A frags [2 slot][2 ks][16 mi] + B1 [2][2][8] + B3 [2][2][8] = 128 KB.
__global__ __launch_bounds__(512, 2)
void gemm1_k(const unsigned short* __restrict__ xcat,
             const unsigned short* __restrict__ w1t, const unsigned short* __restrict__ w3t,
             const unsigned short* __restrict__ rw1t, const unsigned short* __restrict__ rw3t,
             unsigned short* __restrict__ Hcat) {
  int lin = blockIdx.x;
  int work = (lin & 7) * 88 + (lin >> 3);     // 704 = 8 * 88
  int mtile = work / 22, ntile = work - mtile * 22;
  const unsigned short* A = xcat + (size_t)mtile * 256 * DD;
  const unsigned short *B1, *B3;
  if (mtile < 16) { int e = mtile >> 1; B1 = w1t + (size_t)e * FP * DD; B3 = w3t + (size_t)e * FP * DD; }
  else { B1 = rw1t; B3 = rw3t; }
  unsigned short* H = Hcat + (size_t)mtile * 256 * FF;
  int n0 = ntile * 128;

  __shared__ __align__(16) unsigned short lds[65536];   // 128 KB
  char* L = (char*)lds;
  // byte offsets: A: slot*32768 + ks*16384 + mi*1024
  //               B1: 65536 + slot*16384 + ks*8192 + ni*1024
  //               B3: 98304 + slot*16384 + ks*8192 + ni*1024

  int tid = threadIdx.x, l = tid & 63, w = tid >> 6;
  int wm = w >> 1, wn = w & 1;
  int fr = l & 15, fq = l >> 4;
  int srow = l >> 2, soff = STG_CHUNK(l);
  int rdo = RD_OFF(fr, fq);    // element offset within 512-elem frag

  const unsigned short* gA0 = A + (size_t)(w * 16 + srow) * DD + soff;
  const unsigned short* gA1 = A + (size_t)((8 + w) * 16 + srow) * DD + soff;
  const unsigned short* gB1 = B1 + (size_t)(n0 + w * 16 + srow) * DD + soff;
  const unsigned short* gB3 = B3 + (size_t)(n0 + w * 16 + srow) * DD + soff;

#define STAGE1(slot, kt, ks) do { int kk = (kt) * 64 + (ks) * 32;                      \
    GLDS16(gA0 + kk, L + (slot) * 32768 + (ks) * 16384 + w * 1024);                    \
    GLDS16(gA1 + kk, L + (slot) * 32768 + (ks) * 16384 + (8 + w) * 1024);              \
    GLDS16(gB1 + kk, L + 65536 + (slot) * 16384 + (ks) * 8192 + w * 1024);             \
    GLDS16(gB3 + kk, L + 98304 + (slot) * 16384 + (ks) * 8192 + w * 1024); } while (0)

  f32x4 acc1[4][4] = {};
  f32x4 acc3[4][4] = {};

  const int NT = DD / 64;   // 16
  STAGE1(0, 0, 0);
  STAGE1(0, 0, 1);
  STAGE1(1, 1, 0);

  for (int t = 0; t < NT; ++t) {
    int slot = t & 1, nslot = slot ^ 1;
    int t1 = (t + 1 < NT) ? t + 1 : 0;
    int t2 = (t + 2 < NT) ? t + 2 : t + 2 - NT;
    bf16x8 af[4], bf[4];

    // ---- P0: ks0, acc1 ----
    asm volatile("s_waitcnt vmcnt(8)" ::: "memory");
    BAR();
#pragma unroll
    for (int mi = 0; mi < 4; ++mi)
      af[mi] = *(const bf16x8*)(lds + slot * 16384 + (wm * 4 + mi) * 512 + rdo);
#pragma unroll
    for (int ni = 0; ni < 4; ++ni)
      bf[ni] = *(const bf16x8*)(lds + 32768 + slot * 8192 + (wn * 4 + ni) * 512 + rdo);
    STAGE1(nslot, t1, 1);
    __builtin_amdgcn_s_setprio(1);
#pragma unroll
    for (int mi = 0; mi < 4; ++mi)
#pragma unroll
      for (int ni = 0; ni < 4; ++ni)
        acc1[mi][ni] = __builtin_amdgcn_mfma_f32_16x16x32_bf16(af[mi], bf[ni], acc1[mi][ni], 0, 0, 0);
    __builtin_amdgcn_s_setprio(0);

    // ---- P1: ks0, acc3 ----
    BAR();
#pragma unroll
    for (int ni = 0; ni < 4; ++ni)
      bf[ni] = *(const bf16x8*)(lds + 49152 + slot * 8192 + (wn * 4 + ni) * 512 + rdo);
    __builtin_amdgcn_s_setprio(1);
#pragma unroll
    for (int mi = 0; mi < 4; ++mi)
#pragma unroll
      for (int ni = 0; ni < 4; ++ni)
        acc3[mi][ni] = __builtin_amdgcn_mfma_f32_16x16x32_bf16(af[mi], bf[ni], acc3[mi][ni], 0, 0, 0);
    __builtin_amdgcn_s_setprio(0);

    // ---- P2: ks1, acc1 ----
    asm volatile("s_waitcnt vmcnt(8)" ::: "memory");
    BAR();
#pragma unroll
    for (int mi = 0; mi < 4; ++mi)
      af[mi] = *(const bf16x8*)(lds + slot * 16384 + 8192 + (wm * 4 + mi) * 512 + rdo);
#pragma unroll
    for (int ni = 0; ni < 4; ++ni)
      bf[ni] = *(const bf16x8*)(lds + 32768 + slot * 8192 + 4096 + (wn * 4 + ni) * 512 + rdo);
    STAGE1(slot, t2, 0);
    __builtin_amdgcn_s_setprio(1);
#pragma unroll
    for (int mi = 0; mi < 4; ++mi)
#pragma unroll
      for (int ni = 0; ni < 4; ++ni)
        acc1[mi][ni] = __builtin_amdgcn_mfma_f32_16x16x32_bf16(af[mi], bf[ni], acc1[mi][ni], 0, 0, 0);
    __builtin_amdgcn_s_setprio(0);

    // ---- P3: ks1, acc3 ----
    BAR();
#pragma unroll
    for (int ni = 0; ni < 4; ++ni)
      bf[ni] = *(const bf16x8*)(lds + 49152 + slot * 8192 + 4096 + (wn * 4 + ni) * 512 + rdo);
    __builtin_amdgcn_s_setprio(1);
#pragma unroll
    for (int mi = 0; mi < 4; ++mi)
#pragma unroll
      for (int ni = 0; ni < 4; ++ni)
        acc3[mi][ni] = __builtin_amdgcn_mfma_f32_16x16x32_bf16(af[mi], bf[ni], acc3[mi][ni], 0, 0, 0);
    __builtin_amdgcn_s_setprio(0);
  }
#undef STAGE1

#pragma unroll
  for (int mi = 0; mi < 4; ++mi)
#pragma unroll
    for (int ni = 0; ni < 4; ++ni)
#pragma unroll
      for (int r = 0; r < 4; ++r) {
        int gm = wm * 64 + mi * 16 + fq * 4 + r;
        int gn = n0 + wn * 64 + ni * 16 + fr;
        if (gn < FF) {
          float v1 = acc1[mi][ni][r], v3 = acc3[mi][ni][r];
          float h = v1 / (1.0f + __expf(-v1)) * v3;
          H[(size_t)gm * FF + gn] = f2bf(h);
        }
      }
}

// ---------------- GEMM2: Y = H @ W2 ------------------------------
// BM=256, BN=128, BK=64, 8 waves, dbuf LDS, counted-vmcnt 2-phase pipeline.
__global__ __launch_bounds__(512, 2)
void gemm2_k(const unsigned short* __restrict__ Hcat,
             const unsigned short* __restrict__ w2t, const unsigned short* __restrict__ rw2t,
             unsigned short* __restrict__ Ycat) {
  int lin = blockIdx.x;
  int work = (lin & 7) * 32 + (lin >> 3);    // 256 = 8 * 32
  int mtile = work >> 3, ntile = work & 7;
  const unsigned short* A = Hcat + (size_t)mtile * 256 * FF;
  const unsigned short* B = (mtile < 16) ? (w2t + (size_t)(mtile >> 1) * DD * FF) : rw2t;
  unsigned short* Y = Ycat + (size_t)mtile * 256 * DD;
  int n0 = ntile * 128;

  __shared__ __align__(16) unsigned short lds[49152];   // 96 KB
  char* L = (char*)lds;
  // A: slot*32768 + ks*16384 + mi*1024 ; B: 65536 + slot*16384 + ks*8192 + ni*1024

  int tid = threadIdx.x, l = tid & 63, w = tid >> 6;
  int wm = w >> 1, wn = w & 1;
  int fr = l & 15, fq = l >> 4;
  int srow = l >> 2, soff = STG_CHUNK(l);
  int rdo = RD_OFF(fr, fq);

  const unsigned short* gA0 = A + (size_t)(w * 16 + srow) * FF + soff;
  const unsigned short* gA1 = A + (size_t)((8 + w) * 16 + srow) * FF + soff;
  const unsigned short* gB  = B + (size_t)(n0 + w * 16 + srow) * FF + soff;

#define STAGE2(slot, kt, ks) do { int kk = (kt) * 64 + (ks) * 32;                      \
    GLDS16(gA0 + kk, L + (slot) * 32768 + (ks) * 16384 + w * 1024);                    \
    GLDS16(gA1 + kk, L + (slot) * 32768 + (ks) * 16384 + (8 + w) * 1024);              \
    GLDS16(gB  + kk, L + 65536 + (slot) * 16384 + (ks) * 8192 + w * 1024); } while (0)

  f32x4 acc[4][4] = {};

  const int NT = FF / 64;   // 43
  STAGE2(0, 0, 0);
  STAGE2(0, 0, 1);
  STAGE2(1, 1, 0);

  for (int t = 0; t < NT; ++t) {
    int slot = t & 1, nslot = slot ^ 1;
    int t1 = (t + 1 < NT) ? t + 1 : 0;
    int t2 = (t + 2 < NT) ? t + 2 : t + 2 - NT;
    bf16x8 af[4], bf[4];

    // ---- P0: ks0 ----
    asm volatile("s_waitcnt vmcnt(6)" ::: "memory");
    BAR();
#pragma unroll
    for (int mi = 0; mi < 4; ++mi)
      af[mi] = *(const bf16x8*)(lds + slot * 16384 + (wm * 4 + mi) * 512 + rdo);
#pragma unroll
    for (int ni = 0; ni < 4; ++ni)
      bf[ni] = *(const bf16x8*)(lds + 32768 + slot * 8192 + (wn * 4 + ni) * 512 + rdo);
    STAGE2(nslot, t1, 1);
    __builtin_amdgcn_s_setprio(1);
#pragma unroll
    for (int mi = 0; mi < 4; ++mi)
#pragma unroll
      for (int ni = 0; ni < 4; ++ni)
        acc[mi][ni] = __builtin_amdgcn_mfma_f32_16x16x32_bf16(af[mi], bf[ni], acc[mi][ni], 0, 0, 0);
    __builtin_amdgcn_s_setprio(0);

    // ---- P1: ks1 ----
    asm volatile("s_waitcnt vmcnt(6)" ::: "memory");
    BAR();
#pragma unroll
    for (int mi = 0; mi < 4; ++mi)
      af[mi] = *(const bf16x8*)(lds + slot * 16384 + 8192 + (wm * 4 + mi) * 512 + rdo);
#pragma unroll
    for (int ni = 0; ni < 4; ++ni)
      bf[ni] = *(const bf16x8*)(lds + 32768 + slot * 8192 + 4096 + (wn * 4 + ni) * 512 + rdo);
    STAGE2(slot, t2, 0);
    __builtin_amdgcn_s_setprio(1);
#pragma unroll
    for (int mi = 0; mi < 4; ++mi)
#pragma unroll
      for (int ni = 0; ni < 4; ++ni)
        acc[mi][ni] = __builtin_amdgcn_mfma_f32_16x16x32_bf16(af[mi], bf[ni], acc[mi][ni], 0, 0, 0);
    __builtin_amdgcn_s_setprio(0);
  }
#undef STAGE2

#pragma unroll
  for (int mi = 0; mi < 4; ++mi)
#pragma unroll
    for (int ni = 0; ni < 4; ++ni)
#pragma unroll
      for (int r = 0; r < 4; ++r) {
        int gm = wm * 64 + mi * 16 + fq * 4 + r;
        int gn = n0 + wn * 64 + ni * 16 + fr;
        Y[(size_t)gm * DD + gn] = f2bf(acc[mi][ni][r]);
      }
}

// ---------------- combine ----------------------------------------
__global__ void combine_k(const unsigned short* __restrict__ Ye, const unsigned short* __restrict__ Yr,
                          const int* __restrict__ idx, const int* __restrict__ slot,
                          const float* __restrict__ gatev, const float* __restrict__ coef,
                          float* __restrict__ out) {
  int t = blockIdx.x, tid = threadIdx.x;
  int d = tid * 4;
  float c0 = coef[t * 2], c1 = coef[t * 2 + 1];
  int s = slot[t];
  float g = gatev[t] * c0;
  us4 vr = *(const us4*)(Yr + (size_t)t * DD + d);
  float4 o;
  if (s >= 0) {
    us4 ve = *(const us4*)(Ye + ((size_t)idx[t] * CC + s) * DD + d);
    o.x = g * bf2f(ve.x) + c1 * bf2f(vr.x);
    o.y = g * bf2f(ve.y) + c1 * bf2f(vr.y);
    o.z = g * bf2f(ve.z) + c1 * bf2f(vr.z);
    o.w = g * bf2f(ve.w) + c1 * bf2f(vr.w);
  } else {
    o.x = c1 * bf2f(vr.x);
    o.y = c1 * bf2f(vr.y);
    o.z = c1 * bf2f(vr.z);
    o.w = c1 * bf2f(vr.w);
  }
  *(float4*)(out + (size_t)t * DD + d) = o;
}

// ---------------- launch -----------------------------------------
extern "C" void kernel_launch(void* const* d_in, const int* in_sizes, int n_in,
                              void* d_out, int out_size, void* d_ws, size_t ws_size,
                              hipStream_t stream) {
  const float* x   = (const float*)d_in[0];
  const float* wg  = (const float*)d_in[1];
  const float* w1  = (const float*)d_in[2];
  const float* w3  = (const float*)d_in[3];
  const float* w2  = (const float*)d_in[4];
  const float* rw1 = (const float*)d_in[5];
  const float* rw3 = (const float*)d_in[6];
  const float* rw2 = (const float*)d_in[7];
  const float* cw  = (const float*)d_in[8];
  const float* cbv = (const float*)d_in[9];
  float* out = (float*)d_out;

  char* ws = (char*)d_ws;
  size_t o = 0;
  auto alloc = [&](size_t bytes) -> char* {
    char* p = ws + o; o = (o + bytes + 255) & ~(size_t)255; return p;
  };
  unsigned short* w1t  = (unsigned short*)alloc((size_t)EE * FP * DD * 2);
  unsigned short* w3t  = (unsigned short*)alloc((size_t)EE * FP * DD * 2);
  unsigned short* w2t  = (unsigned short*)alloc((size_t)EE * DD * FF * 2);
  unsigned short* rw1t = (unsigned short*)alloc((size_t)FP * DD * 2);
  unsigned short* rw3t = (unsigned short*)alloc((size_t)FP * DD * 2);
  unsigned short* rw2t = (unsigned short*)alloc((size_t)DD * FF * 2);
  // contiguous pairs: xe|xb, He|Hr, Ye|Yr (sizes are 256B-aligned already)
  unsigned short* xe   = (unsigned short*)alloc((size_t)T_TOK * DD * 2);
  unsigned short* xb   = (unsigned short*)alloc((size_t)T_TOK * DD * 2);
  unsigned short* He   = (unsigned short*)alloc((size_t)T_TOK * FF * 2);
  unsigned short* Hr   = (unsigned short*)alloc((size_t)T_TOK * FF * 2);
  unsigned short* Ye   = (unsigned short*)alloc((size_t)T_TOK * DD * 2);
  unsigned short* Yr   = (unsigned short*)alloc((size_t)T_TOK * DD * 2);
  int*   idxp  = (int*)alloc(T_TOK * 4);
  float* gatev = (float*)alloc(T_TOK * 4);
  int*   slotp = (int*)alloc(T_TOK * 4);
  int*   tokp  = (int*)alloc(EE * CC * 4);
  float* coefp = (float*)alloc(T_TOK * 2 * 4);
  float* mep   = (float*)alloc(256);
  if (o > ws_size) return;

  transpose_k<<<dim3(43, 16, EE + 1), 256, 0, stream>>>(w1, rw1, w1t, rw1t, DD, FF, (long)DD * FF, (long)FP * DD);
  transpose_k<<<dim3(43, 16, EE + 1), 256, 0, stream>>>(w3, rw3, w3t, rw3t, DD, FF, (long)DD * FF, (long)FP * DD);
  transpose_k<<<dim3(16, 43, EE + 1), 256, 0, stream>>>(w2, rw2, w2t, rw2t, FF, DD, (long)FF * DD, (long)DD * FF);

  zero_me_k<<<1, 64, 0, stream>>>(mep);
  gate_k<<<T_TOK / 4, 256, 0, stream>>>(x, wg, cw, cbv, idxp, gatev, coefp, mep);
  scan_k<<<1, 512, 0, stream>>>(idxp, mep, slotp, tokp, out + (size_t)T_TOK * DD);
  gather_k<<<2 * T_TOK, 256, 0, stream>>>(x, tokp, xb, xe);
  gemm1_k<<<704, 512, 0, stream>>>(xe, w1t, w3t, rw1t, rw3t, He);
  gemm2_k<<<256, 512, 0, stream>>>(He, w2t, rw2t, Ye);
  combine_k<<<T_TOK, 256, 0, stream>>>(Ye, Yr, idxp, slotp, gatev, coefp, out);
}

// Round 7
// 302.180 us; speedup vs baseline: 1.4713x; 1.0034x over previous
//
#include <hip/hip_runtime.h>
#include <hip/hip_bf16.h>
#include <stdint.h>

#define T_TOK 4096
#define DD 1024
#define EE 8
#define CC 512
#define FF 2752
#define FP 2816

typedef __attribute__((ext_vector_type(8))) short bf16x8;
typedef __attribute__((ext_vector_type(4))) float f32x4;
typedef __attribute__((ext_vector_type(4))) unsigned short us4;

__device__ __forceinline__ float bf2f(unsigned short u) {
  union { float f; unsigned int i; } v; v.i = ((unsigned int)u) << 16; return v.f;
}
__device__ __forceinline__ unsigned short f2bf(float f) {
  union { float f; unsigned int i; } v; v.f = f;
  unsigned int r = v.i + 0x7fffu + ((v.i >> 16) & 1u);
  return (unsigned short)(r >> 16);
}

#define GLDS16(g, l) __builtin_amdgcn_global_load_lds( \
    (const __attribute__((address_space(1))) void*)(g), \
    (__attribute__((address_space(3))) void*)(l), 16, 0, 0)

// Verified swizzle (rounds 3-6): stage-lane l fetches row (l>>2), 16B-chunk
// ((l&3)^((l>>3)&3)); reader lane (fr,fq) at element fr*32 + (fq^((fr>>1)&3))*8.
#define STG_CHUNK(l) (((l & 3) ^ ((l >> 3) & 3)) * 8)
#define RD_OFF(fr, fq) ((fr) * 32 + (((fq) ^ (((fr) >> 1) & 3)) * 8))

#define BAR() do { asm volatile("" ::: "memory"); __builtin_amdgcn_s_barrier(); \
                   asm volatile("" ::: "memory"); } while (0)

// ---------------- weight transpose + f32->bf16 -------------------
__global__ __launch_bounds__(256)
void transpose_k(const float* __restrict__ in, const float* __restrict__ in2,
                 unsigned short* __restrict__ out, unsigned short* __restrict__ out2,
                 int R, int C, long inStride, long outStride) {
  __shared__ unsigned short sm[64][66];
  int b = blockIdx.z;
  if (b < EE) { in += (long)b * inStride; out += (long)b * outStride; }
  else { in = in2; out = out2; }
  int cb = blockIdx.x * 64, rb = blockIdx.y * 64;
  int t = threadIdx.x;
  int rr = t >> 4, c4 = (t & 15) * 4;
#pragma unroll
  for (int i = 0; i < 4; ++i) {
    int r = rr + i * 16;
    float4 v = *(const float4*)(in + (long)(rb + r) * C + cb + c4);
    us4 o; o.x = f2bf(v.x); o.y = f2bf(v.y); o.z = f2bf(v.z); o.w = f2bf(v.w);
    *(us4*)&sm[r][c4] = o;
  }
  __syncthreads();
  int r4 = (t & 15) * 4, cc = t >> 4;
#pragma unroll
  for (int i = 0; i < 4; ++i) {
    int c = cc + i * 16;
    us4 o;
    o.x = sm[r4 + 0][c]; o.y = sm[r4 + 1][c];
    o.z = sm[r4 + 2][c]; o.w = sm[r4 + 3][c];
    *(us4*)(out + (long)(cb + c) * R + rb + r4) = o;
  }
}

__global__ void zero_me_k(float* me) { if (threadIdx.x < EE) me[threadIdx.x] = 0.0f; }

// ---------------- gating ----------------
__global__ void gate_k(const float* __restrict__ x, const float* __restrict__ wg,
                       const float* __restrict__ cw, const float* __restrict__ cbv,
                       int* __restrict__ idx, float* __restrict__ gatev,
                       float* __restrict__ coef, float* __restrict__ me_sum) {
  int tid = threadIdx.x, lane = tid & 63, wv = tid >> 6;
  int t = blockIdx.x * 4 + wv;
  const float* xr = x + (long)t * DD;
  float acc[EE] = {0,0,0,0,0,0,0,0};
  float c0 = 0.0f, c1 = 0.0f;
  for (int d = lane; d < DD; d += 64) {
    float xv = xr[d];
#pragma unroll
    for (int e = 0; e < EE; ++e) acc[e] += xv * wg[d * EE + e];
    c0 += xv * cw[d * 2 + 0];
    c1 += xv * cw[d * 2 + 1];
  }
#pragma unroll
  for (int o = 32; o > 0; o >>= 1) {
#pragma unroll
    for (int e = 0; e < EE; ++e) acc[e] += __shfl_xor(acc[e], o);
    c0 += __shfl_xor(c0, o);
    c1 += __shfl_xor(c1, o);
  }
  __shared__ float sme[EE];
  if (tid < EE) sme[tid] = 0.0f;
  __syncthreads();
  if (lane == 0) {
    float m = acc[0]; int am = 0;
#pragma unroll
    for (int e = 1; e < EE; ++e) if (acc[e] > m) { m = acc[e]; am = e; }
    float g[EE]; float s = 0.0f;
#pragma unroll
    for (int e = 0; e < EE; ++e) { g[e] = __expf(acc[e] - m); s += g[e]; }
    float inv = 1.0f / s;
    idx[t] = am;
    gatev[t] = g[am] * inv;
#pragma unroll
    for (int e = 0; e < EE; ++e) atomicAdd(&sme[e], g[e] * inv);
    float l0 = c0 + cbv[0], l1 = c1 + cbv[1];
    float mm = fmaxf(l0, l1);
    float e0 = __expf(l0 - mm), e1 = __expf(l1 - mm);
    float is = 1.0f / (e0 + e1);
    coef[t * 2 + 0] = e0 * is;
    coef[t * 2 + 1] = e1 * is;
  }
  __syncthreads();
  if (tid < EE) atomicAdd(&me_sum[tid], sme[tid]);
}

// ---------------- capacity scan ----------------
__global__ void scan_k(const int* __restrict__ idx, const float* __restrict__ me_sum,
                       int* __restrict__ slot, int* __restrict__ tok,
                       float* __restrict__ out_tail) {
  __shared__ int sidx[T_TOK];
  __shared__ int counts[EE];
  int tid = threadIdx.x;
  for (int i = tid; i < T_TOK; i += 512) sidx[i] = idx[i];
  __syncthreads();
  int e = tid >> 6, lane = tid & 63;
  int base = 0;
  for (int it = 0; it < T_TOK / 64; ++it) {
    int t = it * 64 + lane;
    bool f = (sidx[t] == e);
    unsigned long long m = __ballot(f);
    if (f) {
      int loc = base + __popcll(m & ((1ull << lane) - 1ull));
      slot[t] = (loc < CC) ? loc : -1;
      if (loc < CC) tok[e * CC + loc] = t;
    }
    base += __popcll(m);
  }
  if (lane == 0) counts[e] = base;
  __syncthreads();
  int filled = min(counts[e], CC);
  for (int c = filled + lane; c < CC; c += 64) tok[e * CC + c] = -1;
  if (tid == 0) {
    float la = 0.0f;
    for (int i = 0; i < EE; ++i) la += me_sum[i] * (float)counts[i];
    la *= (float)EE / ((float)T_TOK * (float)T_TOK);
    out_tail[0] = la;
    for (int i = 0; i < EE; ++i) out_tail[1 + i] = (float)counts[i];
  }
}

// ---------------- gather + bf16 convert ----------------
__global__ void gather_k(const float* __restrict__ x, const int* __restrict__ tok,
                         unsigned short* __restrict__ xb, unsigned short* __restrict__ xe) {
  int r = blockIdx.x, tid = threadIdx.x;
  int d = tid * 4;
  if (r < T_TOK) {
    float4 v = *(const float4*)(x + (long)r * DD + d);
    us4 o; o.x = f2bf(v.x); o.y = f2bf(v.y); o.z = f2bf(v.z); o.w = f2bf(v.w);
    *(us4*)(xb + (long)r * DD + d) = o;
  } else {
    int s = r - T_TOK;
    int t = tok[s];
    us4 o = {0, 0, 0, 0};
    if (t >= 0) {
      float4 v = *(const float4*)(x + (long)t * DD + d);
      o.x = f2bf(v.x); o.y = f2bf(v.y); o.z = f2bf(v.z); o.w = f2bf(v.w);
    }
    *(us4*)(xe + (long)s * DD + d) = o;
  }
}

// ---------------- GEMM1: H = silu(A@W1)*(A@W3) -------------------
// BM=256, BN=128, BK=64, 8 waves, dbuf LDS, counted-vmcnt pipeline.
// 2 barriers per K-tile (P1/P3 barriers proven redundant).
__global__ __launch_bounds__(512, 2)
void gemm1_k(const unsigned short* __restrict__ xcat,
             const unsigned short* __restrict__ w1t, const unsigned short* __restrict__ w3t,
             const unsigned short* __restrict__ rw1t, const unsigned short* __restrict__ rw3t,
             unsigned short* __restrict__ Hcat) {
  int lin = blockIdx.x;
  int work = (lin & 7) * 88 + (lin >> 3);     // 704 = 8 * 88
  int mtile, ntile;
  if (work < 352) {            // experts: ((e*22 + nt)*2 + mt) -> paired mtiles adjacent
    int e = work / 44, r = work - e * 44;
    ntile = r >> 1;
    mtile = e * 2 + (r & 1);
  } else {                     // residual: nt*16 + mt -> 16 consecutive share B panel
    int q = work - 352;
    ntile = q >> 4;
    mtile = 16 + (q & 15);
  }
  const unsigned short* A = xcat + (size_t)mtile * 256 * DD;
  const unsigned short *B1, *B3;
  if (mtile < 16) { int e = mtile >> 1; B1 = w1t + (size_t)e * FP * DD; B3 = w3t + (size_t)e * FP * DD; }
  else { B1 = rw1t; B3 = rw3t; }
  unsigned short* H = Hcat + (size_t)mtile * 256 * FF;
  int n0 = ntile * 128;

  __shared__ __align__(16) unsigned short lds[65536];   // 128 KB
  char* L = (char*)lds;

  int tid = threadIdx.x, l = tid & 63, w = tid >> 6;
  int wm = w >> 1, wn = w & 1;
  int fr = l & 15, fq = l >> 4;
  int srow = l >> 2, soff = STG_CHUNK(l);
  int rdo = RD_OFF(fr, fq);

  const unsigned short* gA0 = A + (size_t)(w * 16 + srow) * DD + soff;
  const unsigned short* gA1 = A + (size_t)((8 + w) * 16 + srow) * DD + soff;
  const unsigned short* gB1 = B1 + (size_t)(n0 + w * 16 + srow) * DD + soff;
  const unsigned short* gB3 = B3 + (size_t)(n0 + w * 16 + srow) * DD + soff;

#define STAGE1(slot, kt, ks) do { int kk = (kt) * 64 + (ks) * 32;                      \
    GLDS16(gA0 + kk, L + (slot) * 32768 + (ks) * 16384 + w * 1024);                    \
    GLDS16(gA1 + kk, L + (slot) * 32768 + (ks) * 16384 + (8 + w) * 1024);              \
    GLDS16(gB1 + kk, L + 65536 + (slot) * 16384 + (ks) * 8192 + w * 1024);             \
    GLDS16(gB3 + kk, L + 98304 + (slot) * 16384 + (ks) * 8192 + w * 1024); } while (0)

  f32x4 acc1[4][4] = {};
  f32x4 acc3[4][4] = {};

  const int NT = DD / 64;   // 16
  STAGE1(0, 0, 0);
  STAGE1(0, 0, 1);
  STAGE1(1, 1, 0);

  for (int t = 0; t < NT; ++t) {
    int slot = t & 1, nslot = slot ^ 1;
    int t1 = (t + 1 < NT) ? t + 1 : 0;
    int t2 = (t + 2 < NT) ? t + 2 : t + 2 - NT;
    bf16x8 af[4], bf[4];

    // ---- P0: ks0, acc1 ----
    asm volatile("s_waitcnt vmcnt(8)" ::: "memory");
    BAR();
#pragma unroll
    for (int mi = 0; mi < 4; ++mi)
      af[mi] = *(const bf16x8*)(lds + slot * 16384 + (wm * 4 + mi) * 512 + rdo);
#pragma unroll
    for (int ni = 0; ni < 4; ++ni)
      bf[ni] = *(const bf16x8*)(lds + 32768 + slot * 8192 + (wn * 4 + ni) * 512 + rdo);
    STAGE1(nslot, t1, 1);
    __builtin_amdgcn_s_setprio(1);
#pragma unroll
    for (int mi = 0; mi < 4; ++mi)
#pragma unroll
      for (int ni = 0; ni < 4; ++ni)
        acc1[mi][ni] = __builtin_amdgcn_mfma_f32_16x16x32_bf16(af[mi], bf[ni], acc1[mi][ni], 0, 0, 0);
    __builtin_amdgcn_s_setprio(0);

    // ---- P1: ks0, acc3 (no barrier: same-arrival data, no slot WAR) ----
#pragma unroll
    for (int ni = 0; ni < 4; ++ni)
      bf[ni] = *(const bf16x8*)(lds + 49152 + slot * 8192 + (wn * 4 + ni) * 512 + rdo);
    __builtin_amdgcn_s_setprio(1);
#pragma unroll
    for (int mi = 0; mi < 4; ++mi)
#pragma unroll
      for (int ni = 0; ni < 4; ++ni)
        acc3[mi][ni] = __builtin_amdgcn_mfma_f32_16x16x32_bf16(af[mi], bf[ni], acc3[mi][ni], 0, 0, 0);
    __builtin_amdgcn_s_setprio(0);

    // ---- P2: ks1, acc1 ----
    asm volatile("s_waitcnt vmcnt(8)" ::: "memory");
    BAR();
#pragma unroll
    for (int mi = 0; mi < 4; ++mi)
      af[mi] = *(const bf16x8*)(lds + slot * 16384 + 8192 + (wm * 4 + mi) * 512 + rdo);
#pragma unroll
    for (int ni = 0; ni < 4; ++ni)
      bf[ni] = *(const bf16x8*)(lds + 32768 + slot * 8192 + 4096 + (wn * 4 + ni) * 512 + rdo);
    STAGE1(slot, t2, 0);
    __builtin_amdgcn_s_setprio(1);
#pragma unroll
    for (int mi = 0; mi < 4; ++mi)
#pragma unroll
      for (int ni = 0; ni < 4; ++ni)
        acc1[mi][ni] = __builtin_amdgcn_mfma_f32_16x16x32_bf16(af[mi], bf[ni], acc1[mi][ni], 0, 0, 0);
    __builtin_amdgcn_s_setprio(0);

    // ---- P3: ks1, acc3 (no barrier) ----
#pragma unroll
    for (int ni = 0; ni < 4; ++ni)
      bf[ni] = *(const bf16x8*)(lds + 49152 + slot * 8192 + 4096 + (wn * 4 + ni) * 512 + rdo);
    __builtin_amdgcn_s_setprio(1);
#pragma unroll
    for (int mi = 0; mi < 4; ++mi)
#pragma unroll
      for (int ni = 0; ni < 4; ++ni)
        acc3[mi][ni] = __builtin_amdgcn_mfma_f32_16x16x32_bf16(af[mi], bf[ni], acc3[mi][ni], 0, 0, 0);
    __builtin_amdgcn_s_setprio(0);
  }
#undef STAGE1

#pragma unroll
  for (int mi = 0; mi < 4; ++mi)
#pragma unroll
    for (int ni = 0; ni < 4; ++ni)
#pragma unroll
      for (int r = 0; r < 4; ++r) {
        int gm = wm * 64 + mi * 16 + fq * 4 + r;
        int gn = n0 + wn * 64 + ni * 16 + fr;
        if (gn < FF) {
          float v1 = acc1[mi][ni][r], v3 = acc3[mi][ni][r];
          float h = v1 / (1.0f + __expf(-v1)) * v3;
          H[(size_t)gm * FF + gn] = f2bf(h);
        }
      }
}

// ---------------- GEMM2: Y = H @ W2 ------------------------------
// BM=256, BN=128, BK=64, 8 waves, dbuf LDS, counted-vmcnt 2-phase pipeline.
__global__ __launch_bounds__(512, 2)
void gemm2_k(const unsigned short* __restrict__ Hcat,
             const unsigned short* __restrict__ w2t, const unsigned short* __restrict__ rw2t,
             unsigned short* __restrict__ Ycat) {
  int lin = blockIdx.x;
  int work = (lin & 7) * 32 + (lin >> 3);    // 256 = 8 * 32
  int mtile, ntile;
  if (work < 128) {            // experts: ((e*8 + nt)*2 + mt)
    int e = work >> 4, r = work & 15;
    ntile = r >> 1;
    mtile = e * 2 + (r & 1);
  } else {                     // residual: nt*16 + mt
    int q = work - 128;
    ntile = q >> 4;
    mtile = 16 + (q & 15);
  }
  const unsigned short* A = Hcat + (size_t)mtile * 256 * FF;
  const unsigned short* B = (mtile < 16) ? (w2t + (size_t)(mtile >> 1) * DD * FF) : rw2t;
  unsigned short* Y = Ycat + (size_t)mtile * 256 * DD;
  int n0 = ntile * 128;

  __shared__ __align__(16) unsigned short lds[49152];   // 96 KB
  char* L = (char*)lds;

  int tid = threadIdx.x, l = tid & 63, w = tid >> 6;
  int wm = w >> 1, wn = w & 1;
  int fr = l & 15, fq = l >> 4;
  int srow = l >> 2, soff = STG_CHUNK(l);
  int rdo = RD_OFF(fr, fq);

  const unsigned short* gA0 = A + (size_t)(w * 16 + srow) * FF + soff;
  const unsigned short* gA1 = A + (size_t)((8 + w) * 16 + srow) * FF + soff;
  const unsigned short* gB  = B + (size_t)(n0 + w * 16 + srow) * FF + soff;

#define STAGE2(slot, kt, ks) do { int kk = (kt) * 64 + (ks) * 32;                      \
    GLDS16(gA0 + kk, L + (slot) * 32768 + (ks) * 16384 + w * 1024);                    \
    GLDS16(gA1 + kk, L + (slot) * 32768 + (ks) * 16384 + (8 + w) * 1024);              \
    GLDS16(gB  + kk, L + 65536 + (slot) * 16384 + (ks) * 8192 + w * 1024); } while (0)

  f32x4 acc[4][4] = {};

  const int NT = FF / 64;   // 43
  STAGE2(0, 0, 0);
  STAGE2(0, 0, 1);
  STAGE2(1, 1, 0);

  for (int t = 0; t < NT; ++t) {
    int slot = t & 1, nslot = slot ^ 1;
    int t1 = (t + 1 < NT) ? t + 1 : 0;
    int t2 = (t + 2 < NT) ? t + 2 : t + 2 - NT;
    bf16x8 af[4], bf[4];

    // ---- P0: ks0 ----
    asm volatile("s_waitcnt vmcnt(6)" ::: "memory");
    BAR();
#pragma unroll
    for (int mi = 0; mi < 4; ++mi)
      af[mi] = *(const bf16x8*)(lds + slot * 16384 + (wm * 4 + mi) * 512 + rdo);
#pragma unroll
    for (int ni = 0; ni < 4; ++ni)
      bf[ni] = *(const bf16x8*)(lds + 32768 + slot * 8192 + (wn * 4 + ni) * 512 + rdo);
    STAGE2(nslot, t1, 1);
    __builtin_amdgcn_s_setprio(1);
#pragma unroll
    for (int mi = 0; mi < 4; ++mi)
#pragma unroll
      for (int ni = 0; ni < 4; ++ni)
        acc[mi][ni] = __builtin_amdgcn_mfma_f32_16x16x32_bf16(af[mi], bf[ni], acc[mi][ni], 0, 0, 0);
    __builtin_amdgcn_s_setprio(0);

    // ---- P1: ks1 ----
    asm volatile("s_waitcnt vmcnt(6)" ::: "memory");
    BAR();
#pragma unroll
    for (int mi = 0; mi < 4; ++mi)
      af[mi] = *(const bf16x8*)(lds + slot * 16384 + 8192 + (wm * 4 + mi) * 512 + rdo);
#pragma unroll
    for (int ni = 0; ni < 4; ++ni)
      bf[ni] = *(const bf16x8*)(lds + 32768 + slot * 8192 + 4096 + (wn * 4 + ni) * 512 + rdo);
    STAGE2(slot, t2, 0);
    __builtin_amdgcn_s_setprio(1);
#pragma unroll
    for (int mi = 0; mi < 4; ++mi)
#pragma unroll
      for (int ni = 0; ni < 4; ++ni)
        acc[mi][ni] = __builtin_amdgcn_mfma_f32_16x16x32_bf16(af[mi], bf[ni], acc[mi][ni], 0, 0, 0);
    __builtin_amdgcn_s_setprio(0);
  }
#undef STAGE2

#pragma unroll
  for (int mi = 0; mi < 4; ++mi)
#pragma unroll
    for (int ni = 0; ni < 4; ++ni)
#pragma unroll
      for (int r = 0; r < 4; ++r) {
        int gm = wm * 64 + mi * 16 + fq * 4 + r;
        int gn = n0 + wn * 64 + ni * 16 + fr;
        Y[(size_t)gm * DD + gn] = f2bf(acc[mi][ni][r]);
      }
}

// ---------------- combine ----------------------------------------
__global__ void combine_k(const unsigned short* __restrict__ Ye, const unsigned short* __restrict__ Yr,
                          const int* __restrict__ idx, const int* __restrict__ slot,
                          const float* __restrict__ gatev, const float* __restrict__ coef,
                          float* __restrict__ out) {
  int t = blockIdx.x, tid = threadIdx.x;
  int d = tid * 4;
  float c0 = coef[t * 2], c1 = coef[t * 2 + 1];
  int s = slot[t];
  float g = gatev[t] * c0;
  us4 vr = *(const us4*)(Yr + (size_t)t * DD + d);
  float4 o;
  if (s >= 0) {
    us4 ve = *(const us4*)(Ye + ((size_t)idx[t] * CC + s) * DD + d);
    o.x = g * bf2f(ve.x) + c1 * bf2f(vr.x);
    o.y = g * bf2f(ve.y) + c1 * bf2f(vr.y);
    o.z = g * bf2f(ve.z) + c1 * bf2f(vr.z);
    o.w = g * bf2f(ve.w) + c1 * bf2f(vr.w);
  } else {
    o.x = c1 * bf2f(vr.x);
    o.y = c1 * bf2f(vr.y);
    o.z = c1 * bf2f(vr.z);
    o.w = c1 * bf2f(vr.w);
  }
  *(float4*)(out + (size_t)t * DD + d) = o;
}

// ---------------- launch -----------------------------------------
extern "C" void kernel_launch(void* const* d_in, const int* in_sizes, int n_in,
                              void* d_out, int out_size, void* d_ws, size_t ws_size,
                              hipStream_t stream) {
  const float* x   = (const float*)d_in[0];
  const float* wg  = (const float*)d_in[1];
  const float* w1  = (const float*)d_in[2];
  const float* w3  = (const float*)d_in[3];
  const float* w2  = (const float*)d_in[4];
  const float* rw1 = (const float*)d_in[5];
  const float* rw3 = (const float*)d_in[6];
  const float* rw2 = (const float*)d_in[7];
  const float* cw  = (const float*)d_in[8];
  const float* cbv = (const float*)d_in[9];
  float* out = (float*)d_out;

  char* ws = (char*)d_ws;
  size_t o = 0;
  auto alloc = [&](size_t bytes) -> char* {
    char* p = ws + o; o = (o + bytes + 255) & ~(size_t)255; return p;
  };
  unsigned short* w1t  = (unsigned short*)alloc((size_t)EE * FP * DD * 2);
  unsigned short* w3t  = (unsigned short*)alloc((size_t)EE * FP * DD * 2);
  unsigned short* w2t  = (unsigned short*)alloc((size_t)EE * DD * FF * 2);
  unsigned short* rw1t = (unsigned short*)alloc((size_t)FP * DD * 2);
  unsigned short* rw3t = (unsigned short*)alloc((size_t)FP * DD * 2);
  unsigned short* rw2t = (unsigned short*)alloc((size_t)DD * FF * 2);
  // contiguous pairs: xe|xb, He|Hr, Ye|Yr
  unsigned short* xe   = (unsigned short*)alloc((size_t)T_TOK * DD * 2);
  unsigned short* xb   = (unsigned short*)alloc((size_t)T_TOK * DD * 2);
  unsigned short* He   = (unsigned short*)alloc((size_t)T_TOK * FF * 2);
  unsigned short* Hr   = (unsigned short*)alloc((size_t)T_TOK * FF * 2);
  unsigned short* Ye   = (unsigned short*)alloc((size_t)T_TOK * DD * 2);
  unsigned short* Yr   = (unsigned short*)alloc((size_t)T_TOK * DD * 2);
  int*   idxp  = (int*)alloc(T_TOK * 4);
  float* gatev = (float*)alloc(T_TOK * 4);
  int*   slotp = (int*)alloc(T_TOK * 4);
  int*   tokp  = (int*)alloc(EE * CC * 4);
  float* coefp = (float*)alloc(T_TOK * 2 * 4);
  float* mep   = (float*)alloc(256);
  if (o > ws_size) return;

  transpose_k<<<dim3(43, 16, EE + 1), 256, 0, stream>>>(w1, rw1, w1t, rw1t, DD, FF, (long)DD * FF, (long)FP * DD);
  transpose_k<<<dim3(43, 16, EE + 1), 256, 0, stream>>>(w3, rw3, w3t, rw3t, DD, FF, (long)DD * FF, (long)FP * DD);
  transpose_k<<<dim3(16, 43, EE + 1), 256, 0, stream>>>(w2, rw2, w2t, rw2t, FF, DD, (long)FF * DD, (long)DD * FF);

  zero_me_k<<<1, 64, 0, stream>>>(mep);
  gate_k<<<T_TOK / 4, 256, 0, stream>>>(x, wg, cw, cbv, idxp, gatev, coefp, mep);
  scan_k<<<1, 512, 0, stream>>>(idxp, mep, slotp, tokp, out + (size_t)T_TOK * DD);
  gather_k<<<2 * T_TOK, 256, 0, stream>>>(x, tokp, xb, xe);
  gemm1_k<<<704, 512, 0, stream>>>(xe, w1t, w3t, rw1t, rw3t, He);
  gemm2_k<<<256, 512, 0, stream>>>(He, w2t, rw2t, Ye);
  combine_k<<<T_TOK, 256, 0, stream>>>(Ye, Yr, idxp, slotp, gatev, coefp, out);
}

// Round 8
// 302.035 us; speedup vs baseline: 1.4720x; 1.0005x over previous
//
#include <hip/hip_runtime.h>
#include <hip/hip_bf16.h>
#include <stdint.h>

#define T_TOK 4096
#define DD 1024
#define EE 8
#define CC 512
#define FF 2752
#define FP 2816

typedef __attribute__((ext_vector_type(8))) short bf16x8;
typedef __attribute__((ext_vector_type(4))) float f32x4;
typedef __attribute__((ext_vector_type(4))) unsigned short us4;
typedef __attribute__((ext_vector_type(8))) unsigned short us8;

__device__ __forceinline__ float bf2f(unsigned short u) {
  union { float f; unsigned int i; } v; v.i = ((unsigned int)u) << 16; return v.f;
}
__device__ __forceinline__ unsigned short f2bf(float f) {
  union { float f; unsigned int i; } v; v.f = f;
  unsigned int r = v.i + 0x7fffu + ((v.i >> 16) & 1u);
  return (unsigned short)(r >> 16);
}

#define GLDS16(g, l) __builtin_amdgcn_global_load_lds( \
    (const __attribute__((address_space(1))) void*)(g), \
    (__attribute__((address_space(3))) void*)(l), 16, 0, 0)

// Verified swizzle (rounds 3-7): stage-lane l fetches row (l>>2), 16B-chunk
// ((l&3)^((l>>3)&3)); reader lane (fr,fq) at element fr*32 + (fq^((fr>>1)&3))*8.
#define STG_CHUNK(l) (((l & 3) ^ ((l >> 3) & 3)) * 8)
#define RD_OFF(fr, fq) ((fr) * 32 + (((fq) ^ (((fr) >> 1) & 3)) * 8))

#define BAR() do { asm volatile("" ::: "memory"); __builtin_amdgcn_s_barrier(); \
                   asm volatile("" ::: "memory"); } while (0)

// ---------------- weight transpose + f32->bf16 (v2) --------------
// in [?][C] f32 -> out [C][R] bf16. Tile RT rows x 64 cols.
// LDS col-swizzle ((r>>3)&7)<<3 keeps us4 writes aligned, cuts read
// conflicts to <=4-way; us8 stores give 16B/lane, 128-256B segments.
template<int RT>
__global__ __launch_bounds__(256)
void transpose_k(const float* __restrict__ in, const float* __restrict__ in2,
                 unsigned short* __restrict__ out, unsigned short* __restrict__ out2,
                 int R, int C, long inStride, long outStride) {
  __shared__ unsigned short sm[RT * 64];
  int b = blockIdx.z;
  if (b < EE) { in += (long)b * inStride; out += (long)b * outStride; }
  else { in = in2; out = out2; }
  int cb = blockIdx.x * 64, rb = blockIdx.y * RT;
  int t = threadIdx.x;
  int rr = t >> 4, c4 = (t & 15) * 4;
#pragma unroll
  for (int i = 0; i < RT / 16; ++i) {
    int r = rr + i * 16;
    float4 v = *(const float4*)(in + (long)(rb + r) * C + cb + c4);
    us4 o; o.x = f2bf(v.x); o.y = f2bf(v.y); o.z = f2bf(v.z); o.w = f2bf(v.w);
    *(us4*)&sm[r * 64 + (c4 ^ (((r >> 3) & 7) << 3))] = o;
  }
  __syncthreads();
#pragma unroll
  for (int j = 0; j < (64 * (RT / 8)) / 256; ++j) {
    int idx = t + j * 256;
    int g, c;
    if (RT == 128) { g = idx & 15; c = idx >> 4; }
    else           { g = idx & 7;  c = idx >> 3; }
    int r8 = g * 8;
    us8 o;
#pragma unroll
    for (int k = 0; k < 8; ++k) {
      int r = r8 + k;
      o[k] = sm[r * 64 + (c ^ (((r >> 3) & 7) << 3))];
    }
    *(us8*)(out + (long)(cb + c) * R + rb + r8) = o;
  }
}

__global__ void zero_me_k(float* me) { if (threadIdx.x < EE) me[threadIdx.x] = 0.0f; }

// ---------------- gating ----------------
__global__ void gate_k(const float* __restrict__ x, const float* __restrict__ wg,
                       const float* __restrict__ cw, const float* __restrict__ cbv,
                       int* __restrict__ idx, float* __restrict__ gatev,
                       float* __restrict__ coef, float* __restrict__ me_sum) {
  int tid = threadIdx.x, lane = tid & 63, wv = tid >> 6;
  int t = blockIdx.x * 4 + wv;
  const float* xr = x + (long)t * DD;
  float acc[EE] = {0,0,0,0,0,0,0,0};
  float c0 = 0.0f, c1 = 0.0f;
  for (int d = lane; d < DD; d += 64) {
    float xv = xr[d];
#pragma unroll
    for (int e = 0; e < EE; ++e) acc[e] += xv * wg[d * EE + e];
    c0 += xv * cw[d * 2 + 0];
    c1 += xv * cw[d * 2 + 1];
  }
#pragma unroll
  for (int o = 32; o > 0; o >>= 1) {
#pragma unroll
    for (int e = 0; e < EE; ++e) acc[e] += __shfl_xor(acc[e], o);
    c0 += __shfl_xor(c0, o);
    c1 += __shfl_xor(c1, o);
  }
  __shared__ float sme[EE];
  if (tid < EE) sme[tid] = 0.0f;
  __syncthreads();
  if (lane == 0) {
    float m = acc[0]; int am = 0;
#pragma unroll
    for (int e = 1; e < EE; ++e) if (acc[e] > m) { m = acc[e]; am = e; }
    float g[EE]; float s = 0.0f;
#pragma unroll
    for (int e = 0; e < EE; ++e) { g[e] = __expf(acc[e] - m); s += g[e]; }
    float inv = 1.0f / s;
    idx[t] = am;
    gatev[t] = g[am] * inv;
#pragma unroll
    for (int e = 0; e < EE; ++e) atomicAdd(&sme[e], g[e] * inv);
    float l0 = c0 + cbv[0], l1 = c1 + cbv[1];
    float mm = fmaxf(l0, l1);
    float e0 = __expf(l0 - mm), e1 = __expf(l1 - mm);
    float is = 1.0f / (e0 + e1);
    coef[t * 2 + 0] = e0 * is;
    coef[t * 2 + 1] = e1 * is;
  }
  __syncthreads();
  if (tid < EE) atomicAdd(&me_sum[tid], sme[tid]);
}

// ---------------- capacity scan ----------------
__global__ void scan_k(const int* __restrict__ idx, const float* __restrict__ me_sum,
                       int* __restrict__ slot, int* __restrict__ tok,
                       float* __restrict__ out_tail) {
  __shared__ int sidx[T_TOK];
  __shared__ int counts[EE];
  int tid = threadIdx.x;
  for (int i = tid; i < T_TOK; i += 512) sidx[i] = idx[i];
  __syncthreads();
  int e = tid >> 6, lane = tid & 63;
  int base = 0;
  for (int it = 0; it < T_TOK / 64; ++it) {
    int t = it * 64 + lane;
    bool f = (sidx[t] == e);
    unsigned long long m = __ballot(f);
    if (f) {
      int loc = base + __popcll(m & ((1ull << lane) - 1ull));
      slot[t] = (loc < CC) ? loc : -1;
      if (loc < CC) tok[e * CC + loc] = t;
    }
    base += __popcll(m);
  }
  if (lane == 0) counts[e] = base;
  __syncthreads();
  int filled = min(counts[e], CC);
  for (int c = filled + lane; c < CC; c += 64) tok[e * CC + c] = -1;
  if (tid == 0) {
    float la = 0.0f;
    for (int i = 0; i < EE; ++i) la += me_sum[i] * (float)counts[i];
    la *= (float)EE / ((float)T_TOK * (float)T_TOK);
    out_tail[0] = la;
    for (int i = 0; i < EE; ++i) out_tail[1 + i] = (float)counts[i];
  }
}

// ---------------- gather + bf16 convert ----------------
__global__ void gather_k(const float* __restrict__ x, const int* __restrict__ tok,
                         unsigned short* __restrict__ xb, unsigned short* __restrict__ xe) {
  int r = blockIdx.x, tid = threadIdx.x;
  int d = tid * 4;
  if (r < T_TOK) {
    float4 v = *(const float4*)(x + (long)r * DD + d);
    us4 o; o.x = f2bf(v.x); o.y = f2bf(v.y); o.z = f2bf(v.z); o.w = f2bf(v.w);
    *(us4*)(xb + (long)r * DD + d) = o;
  } else {
    int s = r - T_TOK;
    int t = tok[s];
    us4 o = {0, 0, 0, 0};
    if (t >= 0) {
      float4 v = *(const float4*)(x + (long)t * DD + d);
      o.x = f2bf(v.x); o.y = f2bf(v.y); o.z = f2bf(v.z); o.w = f2bf(v.w);
    }
    *(us4*)(xe + (long)s * DD + d) = o;
  }
}

// ---------------- GEMM1: H = silu(A@W1)*(A@W3) -------------------
// BM=256, BN=128 dual (B1,B3), BK=64, 8 waves, dbuf LDS.
// m201-style phases: {reads -> stage -> vmcnt -> BAR -> prio1 16xMFMA prio0 -> BAR}
// 4 phases/K-tile: (ks0,acc1)(ks0,acc3)(ks1,acc1)(ks1,acc3).
// Per-tile stage issue order [A0(2), B0(2), A1(2), B1(2)] -> vmcnt(6) after
// staging 2 at PhA/PhC heads drains through the data those phases read.
__global__ __launch_bounds__(512, 2)
void gemm1_k(const unsigned short* __restrict__ xcat,
             const unsigned short* __restrict__ w1t, const unsigned short* __restrict__ w3t,
             const unsigned short* __restrict__ rw1t, const unsigned short* __restrict__ rw3t,
             unsigned short* __restrict__ Hcat) {
  int lin = blockIdx.x;
  int work = (lin & 7) * 88 + (lin >> 3);     // 704 = 8 * 88
  int mtile, ntile;
  if (work < 352) {            // experts: B-panel-sharing mtile pair adjacent
    int e = work / 44, r = work - e * 44;
    ntile = r >> 1;
    mtile = e * 2 + (r & 1);
  } else {                     // residual: 16 consecutive share B panel
    int q = work - 352;
    ntile = q >> 4;
    mtile = 16 + (q & 15);
  }
  const unsigned short* A = xcat + (size_t)mtile * 256 * DD;
  const unsigned short *B1, *B3;
  if (mtile < 16) { int e = mtile >> 1; B1 = w1t + (size_t)e * FP * DD; B3 = w3t + (size_t)e * FP * DD; }
  else { B1 = rw1t; B3 = rw3t; }
  unsigned short* H = Hcat + (size_t)mtile * 256 * FF;
  int n0 = ntile * 128;

  __shared__ __align__(16) unsigned short lds[65536];   // 128 KB
  char* L = (char*)lds;
  // A: s*32768 + ks*16384 + mi16*1024 ; B1: 65536 + s*16384 + ks*8192 + ni8*1024
  // B3: 98304 + s*16384 + ks*8192 + ni8*1024

  int tid = threadIdx.x, l = tid & 63, w = tid >> 6;
  int wm = w >> 1, wn = w & 1;
  int fr = l & 15, fq = l >> 4;
  int srow = l >> 2, soff = STG_CHUNK(l);
  int rdo = RD_OFF(fr, fq);

  const unsigned short* gA0 = A + (size_t)(w * 16 + srow) * DD + soff;
  const unsigned short* gA1 = A + (size_t)((8 + w) * 16 + srow) * DD + soff;
  const unsigned short* gB1 = B1 + (size_t)(n0 + w * 16 + srow) * DD + soff;
  const unsigned short* gB3 = B3 + (size_t)(n0 + w * 16 + srow) * DD + soff;

#define STG_A(ss, kk, ks) do {                                                    \
    GLDS16(gA0 + (kk) + (ks) * 32, L + (ss) * 32768 + (ks) * 16384 + w * 1024);   \
    GLDS16(gA1 + (kk) + (ks) * 32, L + (ss) * 32768 + (ks) * 16384 + (8 + w) * 1024); } while (0)
#define STG_B(ss, kk, ks) do {                                                    \
    GLDS16(gB1 + (kk) + (ks) * 32, L + 65536 + (ss) * 16384 + (ks) * 8192 + w * 1024); \
    GLDS16(gB3 + (kk) + (ks) * 32, L + 98304 + (ss) * 16384 + (ks) * 8192 + w * 1024); } while (0)

  f32x4 acc1[4][4] = {};
  f32x4 acc3[4][4] = {};
  bf16x8 af[4], b1f[4], b3f[4];

  const int NT = DD / 64;   // 16
  // prologue: tile 0 into slot 0, order [A0,B0,A1,B1]
  STG_A(0, 0, 0); STG_B(0, 0, 0); STG_A(0, 0, 1); STG_B(0, 0, 1);

  for (int t = 0; t < NT; ++t) {
    int s = t & 1, ns = s ^ 1;
    int kk1 = ((t + 1 < NT) ? t + 1 : 0) * 64;

    // ---- PhA: ks0, acc1 ----
    STG_A(ns, kk1, 0);
    asm volatile("s_waitcnt vmcnt(6)" ::: "memory");
#pragma unroll
    for (int mi = 0; mi < 4; ++mi)
      af[mi] = *(const bf16x8*)(lds + s * 16384 + (wm * 4 + mi) * 512 + rdo);
#pragma unroll
    for (int ni = 0; ni < 4; ++ni)
      b1f[ni] = *(const bf16x8*)(lds + 32768 + s * 8192 + (wn * 4 + ni) * 512 + rdo);
    BAR();
    __builtin_amdgcn_s_setprio(1);
#pragma unroll
    for (int mi = 0; mi < 4; ++mi)
#pragma unroll
      for (int ni = 0; ni < 4; ++ni)
        acc1[mi][ni] = __builtin_amdgcn_mfma_f32_16x16x32_bf16(af[mi], b1f[ni], acc1[mi][ni], 0, 0, 0);
    __builtin_amdgcn_s_setprio(0);
    BAR();

    // ---- PhB: ks0, acc3 ----
#pragma unroll
    for (int ni = 0; ni < 4; ++ni)
      b3f[ni] = *(const bf16x8*)(lds + 49152 + s * 8192 + (wn * 4 + ni) * 512 + rdo);
    STG_B(ns, kk1, 0);
    BAR();
    __builtin_amdgcn_s_setprio(1);
#pragma unroll
    for (int mi = 0; mi < 4; ++mi)
#pragma unroll
      for (int ni = 0; ni < 4; ++ni)
        acc3[mi][ni] = __builtin_amdgcn_mfma_f32_16x16x32_bf16(af[mi], b3f[ni], acc3[mi][ni], 0, 0, 0);
    __builtin_amdgcn_s_setprio(0);
    BAR();

    // ---- PhC: ks1, acc1 ----
    STG_A(ns, kk1, 1);
    asm volatile("s_waitcnt vmcnt(6)" ::: "memory");
#pragma unroll
    for (int mi = 0; mi < 4; ++mi)
      af[mi] = *(const bf16x8*)(lds + s * 16384 + 8192 + (wm * 4 + mi) * 512 + rdo);
#pragma unroll
    for (int ni = 0; ni < 4; ++ni)
      b1f[ni] = *(const bf16x8*)(lds + 32768 + s * 8192 + 4096 + (wn * 4 + ni) * 512 + rdo);
    BAR();
    __builtin_amdgcn_s_setprio(1);
#pragma unroll
    for (int mi = 0; mi < 4; ++mi)
#pragma unroll
      for (int ni = 0; ni < 4; ++ni)
        acc1[mi][ni] = __builtin_amdgcn_mfma_f32_16x16x32_bf16(af[mi], b1f[ni], acc1[mi][ni], 0, 0, 0);
    __builtin_amdgcn_s_setprio(0);
    BAR();

    // ---- PhD: ks1, acc3 ----
#pragma unroll
    for (int ni = 0; ni < 4; ++ni)
      b3f[ni] = *(const bf16x8*)(lds + 49152 + s * 8192 + 4096 + (wn * 4 + ni) * 512 + rdo);
    STG_B(ns, kk1, 1);
    BAR();
    __builtin_amdgcn_s_setprio(1);
#pragma unroll
    for (int mi = 0; mi < 4; ++mi)
#pragma unroll
      for (int ni = 0; ni < 4; ++ni)
        acc3[mi][ni] = __builtin_amdgcn_mfma_f32_16x16x32_bf16(af[mi], b3f[ni], acc3[mi][ni], 0, 0, 0);
    __builtin_amdgcn_s_setprio(0);
    BAR();
  }
#undef STG_A
#undef STG_B

#pragma unroll
  for (int mi = 0; mi < 4; ++mi)
#pragma unroll
    for (int ni = 0; ni < 4; ++ni)
#pragma unroll
      for (int r = 0; r < 4; ++r) {
        int gm = wm * 64 + mi * 16 + fq * 4 + r;
        int gn = n0 + wn * 64 + ni * 16 + fr;
        if (gn < FF) {
          float v1 = acc1[mi][ni][r], v3 = acc3[mi][ni][r];
          float h = v1 / (1.0f + __expf(-v1)) * v3;
          H[(size_t)gm * FF + gn] = f2bf(h);
        }
      }
}

// ---------------- GEMM2: Y = H @ W2 ------------------------------
// BM=256, BN=128, BK=64, 8 waves, TRI-buffer LDS (144 KB), 2 phases/K-tile,
// prefetch 2 K-tiles ahead -> ~1000cy latency budget, vmcnt(12) counted.
__global__ __launch_bounds__(512, 2)
void gemm2_k(const unsigned short* __restrict__ Hcat,
             const unsigned short* __restrict__ w2t, const unsigned short* __restrict__ rw2t,
             unsigned short* __restrict__ Ycat) {
  int lin = blockIdx.x;
  int work = (lin & 7) * 32 + (lin >> 3);    // 256 = 8 * 32
  int mtile, ntile;
  if (work < 128) {
    int e = work >> 4, r = work & 15;
    ntile = r >> 1;
    mtile = e * 2 + (r & 1);
  } else {
    int q = work - 128;
    ntile = q >> 4;
    mtile = 16 + (q & 15);
  }
  const unsigned short* A = Hcat + (size_t)mtile * 256 * FF;
  const unsigned short* B = (mtile < 16) ? (w2t + (size_t)(mtile >> 1) * DD * FF) : rw2t;
  unsigned short* Y = Ycat + (size_t)mtile * 256 * DD;
  int n0 = ntile * 128;

  __shared__ __align__(16) unsigned short lds[73728];   // 144 KB
  char* L = (char*)lds;
  // A: st*32768 + ks*16384 + mi16*1024 (3 slots, 96KB)
  // B: 98304 + st*16384 + ks*8192 + ni8*1024 (3 slots, 48KB)

  int tid = threadIdx.x, l = tid & 63, w = tid >> 6;
  int wm = w >> 1, wn = w & 1;
  int fr = l & 15, fq = l >> 4;
  int srow = l >> 2, soff = STG_CHUNK(l);
  int rdo = RD_OFF(fr, fq);

  const unsigned short* gA0 = A + (size_t)(w * 16 + srow) * FF + soff;
  const unsigned short* gA1 = A + (size_t)((8 + w) * 16 + srow) * FF + soff;
  const unsigned short* gB  = B + (size_t)(n0 + w * 16 + srow) * FF + soff;

#define STG2(ss, kk, ks) do {                                                        \
    GLDS16(gA0 + (kk) + (ks) * 32, L + (ss) * 32768 + (ks) * 16384 + w * 1024);      \
    GLDS16(gA1 + (kk) + (ks) * 32, L + (ss) * 32768 + (ks) * 16384 + (8 + w) * 1024);\
    GLDS16(gB  + (kk) + (ks) * 32, L + 98304 + (ss) * 16384 + (ks) * 8192 + w * 1024); } while (0)

  f32x4 acc[4][4] = {};
  bf16x8 af[4], bf[4];

  const int NT = FF / 64;   // 43
  // prologue: tiles 0,1 -> slots 0,1 (per-tile order [A0B0, A1B1])
  STG2(0, 0, 0); STG2(0, 0, 1);
  STG2(1, 64, 0); STG2(1, 64, 1);

  for (int t = 0; t < NT; ++t) {
    int st = t % 3;
    int t2 = t + 2; if (t2 >= NT) t2 -= NT;
    int st2 = (st + 2) % 3;
    int kk2 = t2 * 64;

    // ---- PhA: ks0 ----
    STG2(st2, kk2, 0);
    asm volatile("s_waitcnt vmcnt(12)" ::: "memory");
#pragma unroll
    for (int mi = 0; mi < 4; ++mi)
      af[mi] = *(const bf16x8*)(lds + st * 16384 + (wm * 4 + mi) * 512 + rdo);
#pragma unroll
    for (int ni = 0; ni < 4; ++ni)
      bf[ni] = *(const bf16x8*)(lds + 49152 + st * 8192 + (wn * 4 + ni) * 512 + rdo);
    BAR();
    __builtin_amdgcn_s_setprio(1);
#pragma unroll
    for (int mi = 0; mi < 4; ++mi)
#pragma unroll
      for (int ni = 0; ni < 4; ++ni)
        acc[mi][ni] = __builtin_amdgcn_mfma_f32_16x16x32_bf16(af[mi], bf[ni], acc[mi][ni], 0, 0, 0);
    __builtin_amdgcn_s_setprio(0);
    BAR();

    // ---- PhB: ks1 ----
    STG2(st2, kk2, 1);
    asm volatile("s_waitcnt vmcnt(12)" ::: "memory");
#pragma unroll
    for (int mi = 0; mi < 4; ++mi)
      af[mi] = *(const bf16x8*)(lds + st * 16384 + 8192 + (wm * 4 + mi) * 512 + rdo);
#pragma unroll
    for (int ni = 0; ni < 4; ++ni)
      bf[ni] = *(const bf16x8*)(lds + 49152 + st * 8192 + 4096 + (wn * 4 + ni) * 512 + rdo);
    BAR();
    __builtin_amdgcn_s_setprio(1);
#pragma unroll
    for (int mi = 0; mi < 4; ++mi)
#pragma unroll
      for (int ni = 0; ni < 4; ++ni)
        acc[mi][ni] = __builtin_amdgcn_mfma_f32_16x16x32_bf16(af[mi], bf[ni], acc[mi][ni], 0, 0, 0);
    __builtin_amdgcn_s_setprio(0);
    BAR();
  }
#undef STG2

#pragma unroll
  for (int mi = 0; mi < 4; ++mi)
#pragma unroll
    for (int ni = 0; ni < 4; ++ni)
#pragma unroll
      for (int r = 0; r < 4; ++r) {
        int gm = wm * 64 + mi * 16 + fq * 4 + r;
        int gn = n0 + wn * 64 + ni * 16 + fr;
        Y[(size_t)gm * DD + gn] = f2bf(acc[mi][ni][r]);
      }
}

// ---------------- combine ----------------------------------------
__global__ void combine_k(const unsigned short* __restrict__ Ye, const unsigned short* __restrict__ Yr,
                          const int* __restrict__ idx, const int* __restrict__ slot,
                          const float* __restrict__ gatev, const float* __restrict__ coef,
                          float* __restrict__ out) {
  int t = blockIdx.x, tid = threadIdx.x;
  int d = tid * 4;
  float c0 = coef[t * 2], c1 = coef[t * 2 + 1];
  int s = slot[t];
  float g = gatev[t] * c0;
  us4 vr = *(const us4*)(Yr + (size_t)t * DD + d);
  float4 o;
  if (s >= 0) {
    us4 ve = *(const us4*)(Ye + ((size_t)idx[t] * CC + s) * DD + d);
    o.x = g * bf2f(ve.x) + c1 * bf2f(vr.x);
    o.y = g * bf2f(ve.y) + c1 * bf2f(vr.y);
    o.z = g * bf2f(ve.z) + c1 * bf2f(vr.z);
    o.w = g * bf2f(ve.w) + c1 * bf2f(vr.w);
  } else {
    o.x = c1 * bf2f(vr.x);
    o.y = c1 * bf2f(vr.y);
    o.z = c1 * bf2f(vr.z);
    o.w = c1 * bf2f(vr.w);
  }
  *(float4*)(out + (size_t)t * DD + d) = o;
}

// ---------------- launch -----------------------------------------
extern "C" void kernel_launch(void* const* d_in, const int* in_sizes, int n_in,
                              void* d_out, int out_size, void* d_ws, size_t ws_size,
                              hipStream_t stream) {
  const float* x   = (const float*)d_in[0];
  const float* wg  = (const float*)d_in[1];
  const float* w1  = (const float*)d_in[2];
  const float* w3  = (const float*)d_in[3];
  const float* w2  = (const float*)d_in[4];
  const float* rw1 = (const float*)d_in[5];
  const float* rw3 = (const float*)d_in[6];
  const float* rw2 = (const float*)d_in[7];
  const float* cw  = (const float*)d_in[8];
  const float* cbv = (const float*)d_in[9];
  float* out = (float*)d_out;

  char* ws = (char*)d_ws;
  size_t o = 0;
  auto alloc = [&](size_t bytes) -> char* {
    char* p = ws + o; o = (o + bytes + 255) & ~(size_t)255; return p;
  };
  unsigned short* w1t  = (unsigned short*)alloc((size_t)EE * FP * DD * 2);
  unsigned short* w3t  = (unsigned short*)alloc((size_t)EE * FP * DD * 2);
  unsigned short* w2t  = (unsigned short*)alloc((size_t)EE * DD * FF * 2);
  unsigned short* rw1t = (unsigned short*)alloc((size_t)FP * DD * 2);
  unsigned short* rw3t = (unsigned short*)alloc((size_t)FP * DD * 2);
  unsigned short* rw2t = (unsigned short*)alloc((size_t)DD * FF * 2);
  // contiguous pairs: xe|xb, He|Hr, Ye|Yr
  unsigned short* xe   = (unsigned short*)alloc((size_t)T_TOK * DD * 2);
  unsigned short* xb   = (unsigned short*)alloc((size_t)T_TOK * DD * 2);
  unsigned short* He   = (unsigned short*)alloc((size_t)T_TOK * FF * 2);
  unsigned short* Hr   = (unsigned short*)alloc((size_t)T_TOK * FF * 2);
  unsigned short* Ye   = (unsigned short*)alloc((size_t)T_TOK * DD * 2);
  unsigned short* Yr   = (unsigned short*)alloc((size_t)T_TOK * DD * 2);
  int*   idxp  = (int*)alloc(T_TOK * 4);
  float* gatev = (float*)alloc(T_TOK * 4);
  int*   slotp = (int*)alloc(T_TOK * 4);
  int*   tokp  = (int*)alloc(EE * CC * 4);
  float* coefp = (float*)alloc(T_TOK * 2 * 4);
  float* mep   = (float*)alloc(256);
  if (o > ws_size) return;

  // w1/w3: [D][F] -> [F][D], tile 128x64 ; w2: [F][D] -> [D][F], tile 64x64
  transpose_k<128><<<dim3(43, 8, EE + 1), 256, 0, stream>>>(w1, rw1, w1t, rw1t, DD, FF, (long)DD * FF, (long)FP * DD);
  transpose_k<128><<<dim3(43, 8, EE + 1), 256, 0, stream>>>(w3, rw3, w3t, rw3t, DD, FF, (long)DD * FF, (long)FP * DD);
  transpose_k<64><<<dim3(16, 43, EE + 1), 256, 0, stream>>>(w2, rw2, w2t, rw2t, FF, DD, (long)FF * DD, (long)DD * FF);

  zero_me_k<<<1, 64, 0, stream>>>(mep);
  gate_k<<<T_TOK / 4, 256, 0, stream>>>(x, wg, cw, cbv, idxp, gatev, coefp, mep);
  scan_k<<<1, 512, 0, stream>>>(idxp, mep, slotp, tokp, out + (size_t)T_TOK * DD);
  gather_k<<<2 * T_TOK, 256, 0, stream>>>(x, tokp, xb, xe);
  gemm1_k<<<704, 512, 0, stream>>>(xe, w1t, w3t, rw1t, rw3t, He);
  gemm2_k<<<256, 512, 0, stream>>>(He, w2t, rw2t, Ye);
  combine_k<<<T_TOK, 256, 0, stream>>>(Ye, Yr, idxp, slotp, gatev, coefp, out);
}